// Round 1
// baseline (459.276 us; speedup 1.0000x reference)
//
#include <hip/hip_runtime.h>
#include <math.h>

// Problem constants (DRMamba): b=8, c=d_model=96, l=64*64=4096, d_inner=192,
// d_state=16, d_conv=4, dt_rank=6, REVERSE=True (channel flip folded into
// weight indexing on both ends).
#define NBATCH 8
#define SEQL   4096
#define DMODEL 96
#define DINNER 192
#define DSTATE 16
#define NDBC   38      // dt_rank + 2*d_state
#define NCHUNK 64
#define CSTEP  64      // NCHUNK*CSTEP == SEQL

__device__ __forceinline__ float siluf(float x) {
    return x / (1.f + expf(-x));
}
__device__ __forceinline__ float softplusf(float x) {
    return (x > 20.f) ? x : log1pf(expf(x));
}

// ---------------------------------------------------------------------------
// Kernel 1: in_proj GEMM.  out[b,l,j] = sum_m x[b,95-m,l] * w[j,m]
// j<192 -> u_raw, j>=192 -> res.  BM=128 (l), BN=64 (j), K=96 in 3 chunks of 32.
// A is naturally K-major (x is channel-major) -> As[k][row], conflict-free.
// ---------------------------------------------------------------------------
__global__ __launch_bounds__(256) void k_in_proj(const float* __restrict__ x,
                                                 const float* __restrict__ w,
                                                 float* __restrict__ u_raw,
                                                 float* __restrict__ res)
{
    __shared__ float As[32][128];
    __shared__ float Ws[64][36];   // [j][k], pad 36 keeps b128 alignment
    const int tid = threadIdx.x;
    const int tx = tid & 15, ty = tid >> 4;
    const int b = blockIdx.z;
    const int l0 = blockIdx.x * 128;
    const int jb = blockIdx.y * 64;

    float acc[8][4];
#pragma unroll
    for (int r = 0; r < 8; r++)
#pragma unroll
        for (int c = 0; c < 4; c++) acc[r][c] = 0.f;

    for (int kb = 0; kb < 3; kb++) {
        // A tile: 32 m x 128 l, coalesced along l
        {
            const int ll = tid & 127;
            const int mb = tid >> 7;          // 0..1
#pragma unroll
            for (int i = 0; i < 16; i++) {
                const int m = mb + 2 * i;
                As[m][ll] = x[((size_t)b * 96 + (95 - (kb * 32 + m))) * 4096 + l0 + ll];
            }
        }
        // W tile: 64 j x 32 k, float4 along k
        {
            const int k4 = tid & 7;
            const int jb0 = tid >> 3;         // 0..31
#pragma unroll
            for (int i = 0; i < 2; i++) {
                const int jl = jb0 + 32 * i;
                const float4 v = *reinterpret_cast<const float4*>(
                    &w[(size_t)(jb + jl) * 96 + kb * 32 + k4 * 4]);
                *reinterpret_cast<float4*>(&Ws[jl][k4 * 4]) = v;
            }
        }
        __syncthreads();
#pragma unroll
        for (int k = 0; k < 32; k++) {
            const float4 a0 = *reinterpret_cast<const float4*>(&As[k][ty * 8]);
            const float4 a1 = *reinterpret_cast<const float4*>(&As[k][ty * 8 + 4]);
            const float av[8] = {a0.x, a0.y, a0.z, a0.w, a1.x, a1.y, a1.z, a1.w};
            float wv[4];
#pragma unroll
            for (int c = 0; c < 4; c++) wv[c] = Ws[tx * 4 + c][k];
#pragma unroll
            for (int r = 0; r < 8; r++)
#pragma unroll
                for (int c = 0; c < 4; c++) acc[r][c] = fmaf(av[r], wv[c], acc[r][c]);
        }
        __syncthreads();
    }

    float* outp;
    int col0;
    if (jb < 192) { outp = u_raw; col0 = jb + tx * 4; }
    else          { outp = res;   col0 = jb - 192 + tx * 4; }
#pragma unroll
    for (int r = 0; r < 8; r++) {
        const int row = l0 + ty * 8 + r;
        const float4 v = make_float4(acc[r][0], acc[r][1], acc[r][2], acc[r][3]);
        *reinterpret_cast<float4*>(&outp[((size_t)b * 4096 + row) * 192 + col0]) = v;
    }
}

// ---------------------------------------------------------------------------
// Kernel 2: depthwise causal conv1d (k=4) + bias + silu
// ---------------------------------------------------------------------------
__global__ __launch_bounds__(192) void k_conv(const float* __restrict__ u_raw,
                                              const float* __restrict__ cw,
                                              const float* __restrict__ cb,
                                              float* __restrict__ u)
{
    const int d = threadIdx.x;
    const int t = blockIdx.x;
    const int b = blockIdx.y;
    const float4 w4 = *reinterpret_cast<const float4*>(&cw[d * 4]);
    const float wk[4] = {w4.x, w4.y, w4.z, w4.w};
    float s = cb[d];
#pragma unroll
    for (int k = 0; k < 4; k++) {
        const int tt = t - 3 + k;
        if (tt >= 0) s = fmaf(wk[k], u_raw[((size_t)b * 4096 + tt) * 192 + d], s);
    }
    u[((size_t)b * 4096 + t) * 192 + d] = siluf(s);
}

// ---------------------------------------------------------------------------
// Kernel 3: x_proj GEMM.  dbc[b,l,j] = sum_k u[b,l,k] * w[j,k]  (j<38)
// A read direct from global (N-tile count is 1 -> no reuse to exploit),
// W tile in LDS. BM=128, BN=64 (guarded), K=192 in 6 chunks.
// ---------------------------------------------------------------------------
__global__ __launch_bounds__(256) void k_xproj(const float* __restrict__ u,
                                               const float* __restrict__ w,
                                               float* __restrict__ dbc)
{
    __shared__ float Ws[64][36];
    const int tid = threadIdx.x, tx = tid & 15, ty = tid >> 4;
    const int b = blockIdx.z;
    const int l0 = blockIdx.x * 128;

    float acc[8][4];
#pragma unroll
    for (int r = 0; r < 8; r++)
#pragma unroll
        for (int c = 0; c < 4; c++) acc[r][c] = 0.f;

    for (int kb = 0; kb < 6; kb++) {
        {
            const int k4 = tid & 7;
            const int jb0 = tid >> 3;
#pragma unroll
            for (int i = 0; i < 2; i++) {
                const int jl = jb0 + 32 * i;
                float4 v = make_float4(0.f, 0.f, 0.f, 0.f);
                if (jl < NDBC)
                    v = *reinterpret_cast<const float4*>(&w[(size_t)jl * 192 + kb * 32 + k4 * 4]);
                *reinterpret_cast<float4*>(&Ws[jl][k4 * 4]) = v;
            }
        }
        __syncthreads();
#pragma unroll
        for (int k4 = 0; k4 < 8; k4++) {
            float4 a4[8];
#pragma unroll
            for (int r = 0; r < 8; r++) {
                const int row = l0 + ty * 8 + r;
                a4[r] = *reinterpret_cast<const float4*>(
                    &u[((size_t)b * 4096 + row) * 192 + kb * 32 + k4 * 4]);
            }
            float4 w4[4];
#pragma unroll
            for (int c = 0; c < 4; c++)
                w4[c] = *reinterpret_cast<const float4*>(&Ws[tx * 4 + c][k4 * 4]);
#pragma unroll
            for (int r = 0; r < 8; r++)
#pragma unroll
                for (int c = 0; c < 4; c++) {
                    acc[r][c] = fmaf(a4[r].x, w4[c].x, acc[r][c]);
                    acc[r][c] = fmaf(a4[r].y, w4[c].y, acc[r][c]);
                    acc[r][c] = fmaf(a4[r].z, w4[c].z, acc[r][c]);
                    acc[r][c] = fmaf(a4[r].w, w4[c].w, acc[r][c]);
                }
        }
        __syncthreads();
    }
#pragma unroll
    for (int r = 0; r < 8; r++) {
        const int row = l0 + ty * 8 + r;
#pragma unroll
        for (int c = 0; c < 4; c++) {
            const int j = tx * 4 + c;
            if (j < NDBC) dbc[((size_t)b * 4096 + row) * NDBC + j] = acc[r][c];
        }
    }
}

// ---------------------------------------------------------------------------
// Kernel 4: delta = softplus(dt @ dt_proj_w.T + dt_proj_b), K=6
// ---------------------------------------------------------------------------
__global__ __launch_bounds__(768) void k_dtproj(const float* __restrict__ dbc,
                                                const float* __restrict__ w,
                                                const float* __restrict__ bias,
                                                float* __restrict__ delta)
{
    const int j = threadIdx.x;                 // 0..191
    const int row = blockIdx.x * 4 + threadIdx.y;
    const int b = blockIdx.y;
    const size_t g = (size_t)b * 4096 + row;
    const float* dr = &dbc[g * NDBC];
    float s = bias[j];
#pragma unroll
    for (int k = 0; k < 6; k++) s = fmaf(dr[k], w[j * 6 + k], s);
    delta[g * 192 + j] = softplusf(s);
}

// ---------------------------------------------------------------------------
// Scan phase 1: per (b, chunk, d, n): running product of dA and local state
// with zero init over CSTEP steps.
// ---------------------------------------------------------------------------
__global__ __launch_bounds__(256) void k_scan1(const float* __restrict__ delta,
                                               const float* __restrict__ u,
                                               const float* __restrict__ dbc,
                                               const float* __restrict__ A_log,
                                               float* __restrict__ P,
                                               float* __restrict__ S)
{
    const int tid = threadIdx.x;
    const int n = tid & 15, dl = tid >> 4;
    const int c = blockIdx.x, db = blockIdx.y, b = blockIdx.z;
    const int d = db * 16 + dl;
    const float a = -expf(A_log[d * 16 + n]);
    float state = 0.f, p = 1.f;
    const size_t gb = (size_t)b * 4096;
#pragma unroll 4
    for (int t = c * CSTEP; t < c * CSTEP + CSTEP; t++) {
        const size_t g = gb + t;
        const float dt = delta[g * 192 + d];
        const float ut = u[g * 192 + d];
        const float Bt = dbc[g * NDBC + 6 + n];
        const float dA = expf(dt * a);
        p *= dA;
        state = fmaf(dA, state, dt * ut * Bt);
    }
    const size_t idx = (((size_t)b * NCHUNK + c) * 192 + d) * 16 + n;
    P[idx] = p;
    S[idx] = state;
}

// ---------------------------------------------------------------------------
// Scan phase 2: sequential combine over chunks; S[c] is overwritten in place
// with the init state for chunk c (carry BEFORE processing chunk c).
// ---------------------------------------------------------------------------
__global__ __launch_bounds__(256) void k_scan2(const float* __restrict__ P,
                                               float* __restrict__ S)
{
    const int dn = blockIdx.x * 256 + threadIdx.x;   // 0..3071
    const int b = blockIdx.y;
    float carry = 0.f;
    for (int c = 0; c < NCHUNK; c++) {
        const size_t idx = ((size_t)b * NCHUNK + c) * 3072 + dn;
        const float p = P[idx];
        const float s = S[idx];
        S[idx] = carry;
        carry = fmaf(p, carry, s);
    }
}

// ---------------------------------------------------------------------------
// Scan phase 3: re-run recurrence from correct init, reduce y over n (16-lane
// butterfly), fused epilogue y_final = (y + u*D) * silu(res).
// ---------------------------------------------------------------------------
__global__ __launch_bounds__(256) void k_scan3(const float* __restrict__ delta,
                                               const float* __restrict__ u,
                                               const float* __restrict__ dbc,
                                               const float* __restrict__ A_log,
                                               const float* __restrict__ S,
                                               const float* __restrict__ Dp,
                                               const float* __restrict__ res,
                                               float* __restrict__ y)
{
    const int tid = threadIdx.x;
    const int n = tid & 15, dl = tid >> 4;
    const int c = blockIdx.x, db = blockIdx.y, b = blockIdx.z;
    const int d = db * 16 + dl;
    const float a = -expf(A_log[d * 16 + n]);
    const float Dd = Dp[d];
    float state = S[(((size_t)b * NCHUNK + c) * 192 + d) * 16 + n];
    const size_t gb = (size_t)b * 4096;
#pragma unroll 2
    for (int t = c * CSTEP; t < c * CSTEP + CSTEP; t++) {
        const size_t g = gb + t;
        const float dt = delta[g * 192 + d];
        const float ut = u[g * 192 + d];
        const float Bt = dbc[g * NDBC + 6 + n];
        const float Ct = dbc[g * NDBC + 22 + n];
        const float dA = expf(dt * a);
        state = fmaf(dA, state, dt * ut * Bt);
        float yt = state * Ct;
        yt += __shfl_xor(yt, 1);
        yt += __shfl_xor(yt, 2);
        yt += __shfl_xor(yt, 4);
        yt += __shfl_xor(yt, 8);
        if (n == 0) {
            const float yf = fmaf(ut, Dd, yt);
            const float r = res[g * 192 + d];
            y[g * 192 + d] = yf * siluf(r);
        }
    }
}

// ---------------------------------------------------------------------------
// Kernel 8: out_proj GEMM with output transpose + channel flip.
// d_out[b, 95-j, l] = sum_k y[b,l,k] * w[j,k]
// ---------------------------------------------------------------------------
__global__ __launch_bounds__(256) void k_outproj(const float* __restrict__ y,
                                                 const float* __restrict__ w,
                                                 float* __restrict__ out)
{
    __shared__ float Ws[64][36];
    const int tid = threadIdx.x, tx = tid & 15, ty = tid >> 4;
    const int b = blockIdx.z;
    const int l0 = blockIdx.x * 128;
    const int jb = blockIdx.y * 64;

    float acc[8][4];
#pragma unroll
    for (int r = 0; r < 8; r++)
#pragma unroll
        for (int c = 0; c < 4; c++) acc[r][c] = 0.f;

    for (int kb = 0; kb < 6; kb++) {
        {
            const int k4 = tid & 7;
            const int jb0 = tid >> 3;
#pragma unroll
            for (int i = 0; i < 2; i++) {
                const int jl = jb0 + 32 * i;
                const int j = jb + jl;
                float4 v = make_float4(0.f, 0.f, 0.f, 0.f);
                if (j < 96)
                    v = *reinterpret_cast<const float4*>(&w[(size_t)j * 192 + kb * 32 + k4 * 4]);
                *reinterpret_cast<float4*>(&Ws[jl][k4 * 4]) = v;
            }
        }
        __syncthreads();
#pragma unroll
        for (int k4 = 0; k4 < 8; k4++) {
            float4 a4[8];
#pragma unroll
            for (int r = 0; r < 8; r++) {
                const int row = l0 + ty * 8 + r;
                a4[r] = *reinterpret_cast<const float4*>(
                    &y[((size_t)b * 4096 + row) * 192 + kb * 32 + k4 * 4]);
            }
            float4 w4[4];
#pragma unroll
            for (int c = 0; c < 4; c++)
                w4[c] = *reinterpret_cast<const float4*>(&Ws[tx * 4 + c][k4 * 4]);
#pragma unroll
            for (int r = 0; r < 8; r++)
#pragma unroll
                for (int c = 0; c < 4; c++) {
                    acc[r][c] = fmaf(a4[r].x, w4[c].x, acc[r][c]);
                    acc[r][c] = fmaf(a4[r].y, w4[c].y, acc[r][c]);
                    acc[r][c] = fmaf(a4[r].z, w4[c].z, acc[r][c]);
                    acc[r][c] = fmaf(a4[r].w, w4[c].w, acc[r][c]);
                }
        }
        __syncthreads();
    }
#pragma unroll
    for (int c = 0; c < 4; c++) {
        const int j = jb + tx * 4 + c;
        if (j < 96) {
            const int ch = 95 - j;
            const float4 v0 = make_float4(acc[0][c], acc[1][c], acc[2][c], acc[3][c]);
            const float4 v1 = make_float4(acc[4][c], acc[5][c], acc[6][c], acc[7][c]);
            const size_t base = ((size_t)b * 96 + ch) * 4096 + l0 + ty * 8;
            *reinterpret_cast<float4*>(&out[base]) = v0;
            *reinterpret_cast<float4*>(&out[base + 4]) = v1;
        }
    }
}

extern "C" void kernel_launch(void* const* d_in, const int* in_sizes, int n_in,
                              void* d_out, int out_size, void* d_ws, size_t ws_size,
                              hipStream_t stream)
{
    const float* x       = (const float*)d_in[0];
    const float* in_w    = (const float*)d_in[1];
    const float* conv_w  = (const float*)d_in[2];
    const float* conv_b  = (const float*)d_in[3];
    const float* xproj_w = (const float*)d_in[4];
    const float* dt_w    = (const float*)d_in[5];
    const float* dt_b    = (const float*)d_in[6];
    const float* A_log   = (const float*)d_in[7];
    const float* Dp      = (const float*)d_in[8];
    const float* out_w   = (const float*)d_in[9];

    // workspace layout (floats). total = 29,556,736 floats = 113 MB
    float* ws    = (float*)d_ws;
    float* u_raw = ws;                        // 6291456  (reused as y_final later)
    float* res   = u_raw + 6291456;           // 6291456
    float* u     = res   + 6291456;           // 6291456
    float* delta = u     + 6291456;           // 6291456
    float* dbc   = delta + 6291456;           // 1245184
    float* P     = dbc   + 1245184;           // 1572864
    float* S     = P     + 1572864;           // 1572864
    float* yfin  = u_raw;                     // alias: u_raw dead after conv

    hipLaunchKernelGGL(k_in_proj, dim3(32, 6, 8), dim3(256), 0, stream, x, in_w, u_raw, res);
    hipLaunchKernelGGL(k_conv,    dim3(4096, 8),  dim3(192), 0, stream, u_raw, conv_w, conv_b, u);
    hipLaunchKernelGGL(k_xproj,   dim3(32, 1, 8), dim3(256), 0, stream, u, xproj_w, dbc);
    hipLaunchKernelGGL(k_dtproj,  dim3(1024, 8),  dim3(192, 4), 0, stream, dbc, dt_w, dt_b, delta);
    hipLaunchKernelGGL(k_scan1,   dim3(NCHUNK, 12, 8), dim3(256), 0, stream, delta, u, dbc, A_log, P, S);
    hipLaunchKernelGGL(k_scan2,   dim3(12, 8),    dim3(256), 0, stream, P, S);
    hipLaunchKernelGGL(k_scan3,   dim3(NCHUNK, 12, 8), dim3(256), 0, stream, delta, u, dbc, A_log, S, Dp, res, yfin);
    hipLaunchKernelGGL(k_outproj, dim3(32, 2, 8), dim3(256), 0, stream, yfin, out_w, (float*)d_out);
}

// Round 2
// 315.965 us; speedup vs baseline: 1.4536x; 1.4536x over previous
//
#include <hip/hip_runtime.h>
#include <math.h>

// Problem constants (DRMamba): b=8, c=d_model=96, l=64*64=4096, d_inner=192,
// d_state=16, d_conv=4, dt_rank=6, REVERSE=True (channel flip folded into
// weight indexing on both ends).
#define NBATCH 8
#define SEQL   4096
#define DMODEL 96
#define DINNER 192
#define DSTATE 16
#define NDBC   38      // dt_rank + 2*d_state
#define NCHUNK 128
#define CSTEP  32      // NCHUNK*CSTEP == SEQL

__device__ __forceinline__ float siluf(float x) {
    return x / (1.f + expf(-x));
}
__device__ __forceinline__ float softplusf(float x) {
    return (x > 20.f) ? x : log1pf(expf(x));
}

// ---------------------------------------------------------------------------
// Kernel 1: in_proj GEMM.  out[b,l,j] = sum_m x[b,95-m,l] * w[j,m]
// j<192 -> u_raw, j>=192 -> res.  BM=128 (l), BN=64 (j), K=96 in 3 chunks of 32.
// ---------------------------------------------------------------------------
__global__ __launch_bounds__(256) void k_in_proj(const float* __restrict__ x,
                                                 const float* __restrict__ w,
                                                 float* __restrict__ u_raw,
                                                 float* __restrict__ res)
{
    __shared__ float As[32][128];
    __shared__ float Ws[64][36];   // [j][k], pad 36 keeps b128 alignment
    const int tid = threadIdx.x;
    const int tx = tid & 15, ty = tid >> 4;
    const int b = blockIdx.z;
    const int l0 = blockIdx.x * 128;
    const int jb = blockIdx.y * 64;

    float acc[8][4];
#pragma unroll
    for (int r = 0; r < 8; r++)
#pragma unroll
        for (int c = 0; c < 4; c++) acc[r][c] = 0.f;

    for (int kb = 0; kb < 3; kb++) {
        {
            const int ll = tid & 127;
            const int mb = tid >> 7;          // 0..1
#pragma unroll
            for (int i = 0; i < 16; i++) {
                const int m = mb + 2 * i;
                As[m][ll] = x[((size_t)b * 96 + (95 - (kb * 32 + m))) * 4096 + l0 + ll];
            }
        }
        {
            const int k4 = tid & 7;
            const int jb0 = tid >> 3;         // 0..31
#pragma unroll
            for (int i = 0; i < 2; i++) {
                const int jl = jb0 + 32 * i;
                const float4 v = *reinterpret_cast<const float4*>(
                    &w[(size_t)(jb + jl) * 96 + kb * 32 + k4 * 4]);
                *reinterpret_cast<float4*>(&Ws[jl][k4 * 4]) = v;
            }
        }
        __syncthreads();
#pragma unroll
        for (int k = 0; k < 32; k++) {
            const float4 a0 = *reinterpret_cast<const float4*>(&As[k][ty * 8]);
            const float4 a1 = *reinterpret_cast<const float4*>(&As[k][ty * 8 + 4]);
            const float av[8] = {a0.x, a0.y, a0.z, a0.w, a1.x, a1.y, a1.z, a1.w};
            float wv[4];
#pragma unroll
            for (int c = 0; c < 4; c++) wv[c] = Ws[tx * 4 + c][k];
#pragma unroll
            for (int r = 0; r < 8; r++)
#pragma unroll
                for (int c = 0; c < 4; c++) acc[r][c] = fmaf(av[r], wv[c], acc[r][c]);
        }
        __syncthreads();
    }

    float* outp;
    int col0;
    if (jb < 192) { outp = u_raw; col0 = jb + tx * 4; }
    else          { outp = res;   col0 = jb - 192 + tx * 4; }
#pragma unroll
    for (int r = 0; r < 8; r++) {
        const int row = l0 + ty * 8 + r;
        const float4 v = make_float4(acc[r][0], acc[r][1], acc[r][2], acc[r][3]);
        *reinterpret_cast<float4*>(&outp[((size_t)b * 4096 + row) * 192 + col0]) = v;
    }
}

// ---------------------------------------------------------------------------
// Kernel 2: depthwise causal conv1d (k=4) + bias + silu
// ---------------------------------------------------------------------------
__global__ __launch_bounds__(192) void k_conv(const float* __restrict__ u_raw,
                                              const float* __restrict__ cw,
                                              const float* __restrict__ cb,
                                              float* __restrict__ u)
{
    const int d = threadIdx.x;
    const int t = blockIdx.x;
    const int b = blockIdx.y;
    const float4 w4 = *reinterpret_cast<const float4*>(&cw[d * 4]);
    const float wk[4] = {w4.x, w4.y, w4.z, w4.w};
    float s = cb[d];
#pragma unroll
    for (int k = 0; k < 4; k++) {
        const int tt = t - 3 + k;
        if (tt >= 0) s = fmaf(wk[k], u_raw[((size_t)b * 4096 + tt) * 192 + d], s);
    }
    u[((size_t)b * 4096 + t) * 192 + d] = siluf(s);
}

// ---------------------------------------------------------------------------
// Kernel 3: x_proj GEMM.  dbc[j] = sum_k u[b,l,k] * w[j,k]  (j<38)
// j 0..5 -> dbc (for dt_proj), j 6..21 -> Barr, j 22..37 -> Carr (64B-aligned
// rows of 16 so the scan kernels can float4-load them).
// ---------------------------------------------------------------------------
__global__ __launch_bounds__(256) void k_xproj(const float* __restrict__ u,
                                               const float* __restrict__ w,
                                               float* __restrict__ dbc,
                                               float* __restrict__ Barr,
                                               float* __restrict__ Carr)
{
    __shared__ float Ws[64][36];
    const int tid = threadIdx.x, tx = tid & 15, ty = tid >> 4;
    const int b = blockIdx.z;
    const int l0 = blockIdx.x * 128;

    float acc[8][4];
#pragma unroll
    for (int r = 0; r < 8; r++)
#pragma unroll
        for (int c = 0; c < 4; c++) acc[r][c] = 0.f;

    for (int kb = 0; kb < 6; kb++) {
        {
            const int k4 = tid & 7;
            const int jb0 = tid >> 3;
#pragma unroll
            for (int i = 0; i < 2; i++) {
                const int jl = jb0 + 32 * i;
                float4 v = make_float4(0.f, 0.f, 0.f, 0.f);
                if (jl < NDBC)
                    v = *reinterpret_cast<const float4*>(&w[(size_t)jl * 192 + kb * 32 + k4 * 4]);
                *reinterpret_cast<float4*>(&Ws[jl][k4 * 4]) = v;
            }
        }
        __syncthreads();
#pragma unroll
        for (int k4 = 0; k4 < 8; k4++) {
            float4 a4[8];
#pragma unroll
            for (int r = 0; r < 8; r++) {
                const int row = l0 + ty * 8 + r;
                a4[r] = *reinterpret_cast<const float4*>(
                    &u[((size_t)b * 4096 + row) * 192 + kb * 32 + k4 * 4]);
            }
            float4 w4[4];
#pragma unroll
            for (int c = 0; c < 4; c++)
                w4[c] = *reinterpret_cast<const float4*>(&Ws[tx * 4 + c][k4 * 4]);
#pragma unroll
            for (int r = 0; r < 8; r++)
#pragma unroll
                for (int c = 0; c < 4; c++) {
                    acc[r][c] = fmaf(a4[r].x, w4[c].x, acc[r][c]);
                    acc[r][c] = fmaf(a4[r].y, w4[c].y, acc[r][c]);
                    acc[r][c] = fmaf(a4[r].z, w4[c].z, acc[r][c]);
                    acc[r][c] = fmaf(a4[r].w, w4[c].w, acc[r][c]);
                }
        }
        __syncthreads();
    }
#pragma unroll
    for (int r = 0; r < 8; r++) {
        const size_t row = (size_t)blockIdx.z * 4096 + l0 + ty * 8 + r;
#pragma unroll
        for (int c = 0; c < 4; c++) {
            const int j = tx * 4 + c;
            if (j < 6)       dbc[row * NDBC + j] = acc[r][c];
            else if (j < 22) Barr[row * 16 + (j - 6)] = acc[r][c];
            else if (j < 38) Carr[row * 16 + (j - 22)] = acc[r][c];
        }
    }
}

// ---------------------------------------------------------------------------
// Kernel 4: delta = softplus(dt @ dt_proj_w.T + dt_proj_b), K=6
// ---------------------------------------------------------------------------
__global__ __launch_bounds__(768) void k_dtproj(const float* __restrict__ dbc,
                                                const float* __restrict__ w,
                                                const float* __restrict__ bias,
                                                float* __restrict__ delta)
{
    const int j = threadIdx.x;                 // 0..191
    const int row = blockIdx.x * 4 + threadIdx.y;
    const int b = blockIdx.y;
    const size_t g = (size_t)b * 4096 + row;
    const float* dr = &dbc[g * NDBC];
    float s = bias[j];
#pragma unroll
    for (int k = 0; k < 6; k++) s = fmaf(dr[k], w[j * 6 + k], s);
    delta[g * 192 + j] = softplusf(s);
}

// ---------------------------------------------------------------------------
// Scan phase 1: one thread per (b, d, chunk); all 16 n in registers.
// Computes running product P[n] of dA and local state S[n] (zero init).
// ---------------------------------------------------------------------------
__global__ __launch_bounds__(192) void k_scan1(const float* __restrict__ delta,
                                               const float* __restrict__ u,
                                               const float* __restrict__ Barr,
                                               const float* __restrict__ A_log,
                                               float* __restrict__ P,
                                               float* __restrict__ S)
{
    const int d = threadIdx.x;                 // 0..191 (64 consecutive d / wave)
    const int c = blockIdx.x;                  // chunk
    const int b = blockIdx.y;

    float a[16];
    {
        const float4* al = reinterpret_cast<const float4*>(&A_log[d * 16]);
#pragma unroll
        for (int i = 0; i < 4; i++) {
            const float4 v = al[i];
            a[4 * i + 0] = -expf(v.x);
            a[4 * i + 1] = -expf(v.y);
            a[4 * i + 2] = -expf(v.z);
            a[4 * i + 3] = -expf(v.w);
        }
    }
    float st[16], p[16];
#pragma unroll
    for (int n = 0; n < 16; n++) { st[n] = 0.f; p[n] = 1.f; }

    const size_t g0 = (size_t)b * 4096 + (size_t)c * CSTEP;
    const float* dp = delta + g0 * 192 + d;
    const float* up = u + g0 * 192 + d;
    const float* bp = Barr + g0 * 16;

#pragma unroll 2
    for (int t = 0; t < CSTEP; t++) {
        const float dt = dp[t * 192];
        const float dtu = dt * up[t * 192];
        float Bv[16];
        {
            const float4* b4 = reinterpret_cast<const float4*>(bp + t * 16);
#pragma unroll
            for (int i = 0; i < 4; i++) {
                const float4 v = b4[i];
                Bv[4 * i + 0] = v.x; Bv[4 * i + 1] = v.y;
                Bv[4 * i + 2] = v.z; Bv[4 * i + 3] = v.w;
            }
        }
#pragma unroll
        for (int n = 0; n < 16; n++) {
            const float dA = __expf(dt * a[n]);
            p[n] *= dA;
            st[n] = fmaf(dA, st[n], dtu * Bv[n]);
        }
    }

    const size_t idx = (((size_t)b * NCHUNK + c) * 192 + d) * 16;
    float4* Pp = reinterpret_cast<float4*>(&P[idx]);
    float4* Sp = reinterpret_cast<float4*>(&S[idx]);
#pragma unroll
    for (int i = 0; i < 4; i++) {
        Pp[i] = make_float4(p[4 * i], p[4 * i + 1], p[4 * i + 2], p[4 * i + 3]);
        Sp[i] = make_float4(st[4 * i], st[4 * i + 1], st[4 * i + 2], st[4 * i + 3]);
    }
}

// ---------------------------------------------------------------------------
// Scan phase 2: sequential combine over chunks; S[c] overwritten with the
// init state for chunk c (carry BEFORE chunk c). Unrolled so loads pipeline.
// ---------------------------------------------------------------------------
__global__ __launch_bounds__(256) void k_scan2(const float* __restrict__ P,
                                               float* __restrict__ S)
{
    const int dn = blockIdx.x * 256 + threadIdx.x;   // 0..3071
    const int b = blockIdx.y;
    float carry = 0.f;
    const size_t base = (size_t)b * NCHUNK * 3072 + dn;
#pragma unroll 8
    for (int c = 0; c < NCHUNK; c++) {
        const size_t idx = base + (size_t)c * 3072;
        const float p = P[idx];
        const float s = S[idx];
        S[idx] = carry;
        carry = fmaf(p, carry, s);
    }
}

// ---------------------------------------------------------------------------
// Scan phase 3: re-run recurrence from correct init; y reduced in-register
// over n; fused epilogue y = (y + u*D) * silu(res).
// ---------------------------------------------------------------------------
__global__ __launch_bounds__(192) void k_scan3(const float* __restrict__ delta,
                                               const float* __restrict__ u,
                                               const float* __restrict__ Barr,
                                               const float* __restrict__ Carr,
                                               const float* __restrict__ A_log,
                                               const float* __restrict__ S,
                                               const float* __restrict__ Dp,
                                               const float* __restrict__ res,
                                               float* __restrict__ y)
{
    const int d = threadIdx.x;
    const int c = blockIdx.x;
    const int b = blockIdx.y;

    float a[16];
    {
        const float4* al = reinterpret_cast<const float4*>(&A_log[d * 16]);
#pragma unroll
        for (int i = 0; i < 4; i++) {
            const float4 v = al[i];
            a[4 * i + 0] = -expf(v.x);
            a[4 * i + 1] = -expf(v.y);
            a[4 * i + 2] = -expf(v.z);
            a[4 * i + 3] = -expf(v.w);
        }
    }
    float st[16];
    {
        const float4* Sp = reinterpret_cast<const float4*>(
            &S[(((size_t)b * NCHUNK + c) * 192 + d) * 16]);
#pragma unroll
        for (int i = 0; i < 4; i++) {
            const float4 v = Sp[i];
            st[4 * i + 0] = v.x; st[4 * i + 1] = v.y;
            st[4 * i + 2] = v.z; st[4 * i + 3] = v.w;
        }
    }
    const float Dd = Dp[d];

    const size_t g0 = (size_t)b * 4096 + (size_t)c * CSTEP;
    const float* dp = delta + g0 * 192 + d;
    const float* up = u + g0 * 192 + d;
    const float* rp = res + g0 * 192 + d;
    float* yp = y + g0 * 192 + d;
    const float* bp = Barr + g0 * 16;
    const float* cp = Carr + g0 * 16;

#pragma unroll 2
    for (int t = 0; t < CSTEP; t++) {
        const float dt = dp[t * 192];
        const float ut = up[t * 192];
        const float dtu = dt * ut;
        float Bv[16], Cv[16];
        {
            const float4* b4 = reinterpret_cast<const float4*>(bp + t * 16);
            const float4* c4 = reinterpret_cast<const float4*>(cp + t * 16);
#pragma unroll
            for (int i = 0; i < 4; i++) {
                const float4 v = b4[i];
                Bv[4 * i + 0] = v.x; Bv[4 * i + 1] = v.y;
                Bv[4 * i + 2] = v.z; Bv[4 * i + 3] = v.w;
                const float4 w = c4[i];
                Cv[4 * i + 0] = w.x; Cv[4 * i + 1] = w.y;
                Cv[4 * i + 2] = w.z; Cv[4 * i + 3] = w.w;
            }
        }
        float yt = 0.f;
#pragma unroll
        for (int n = 0; n < 16; n++) {
            const float dA = __expf(dt * a[n]);
            st[n] = fmaf(dA, st[n], dtu * Bv[n]);
            yt = fmaf(st[n], Cv[n], yt);
        }
        const float r = rp[t * 192];
        const float sig = __builtin_amdgcn_rcpf(1.f + __expf(-r));
        yp[t * 192] = fmaf(ut, Dd, yt) * (r * sig);
    }
}

// ---------------------------------------------------------------------------
// Kernel 8: out_proj GEMM with output transpose + channel flip.
// d_out[b, 95-j, l] = sum_k y[b,l,k] * w[j,k]
// ---------------------------------------------------------------------------
__global__ __launch_bounds__(256) void k_outproj(const float* __restrict__ y,
                                                 const float* __restrict__ w,
                                                 float* __restrict__ out)
{
    __shared__ float Ws[64][36];
    const int tid = threadIdx.x, tx = tid & 15, ty = tid >> 4;
    const int b = blockIdx.z;
    const int l0 = blockIdx.x * 128;
    const int jb = blockIdx.y * 64;

    float acc[8][4];
#pragma unroll
    for (int r = 0; r < 8; r++)
#pragma unroll
        for (int c = 0; c < 4; c++) acc[r][c] = 0.f;

    for (int kb = 0; kb < 6; kb++) {
        {
            const int k4 = tid & 7;
            const int jb0 = tid >> 3;
#pragma unroll
            for (int i = 0; i < 2; i++) {
                const int jl = jb0 + 32 * i;
                const int j = jb + jl;
                float4 v = make_float4(0.f, 0.f, 0.f, 0.f);
                if (j < 96)
                    v = *reinterpret_cast<const float4*>(&w[(size_t)j * 192 + kb * 32 + k4 * 4]);
                *reinterpret_cast<float4*>(&Ws[jl][k4 * 4]) = v;
            }
        }
        __syncthreads();
#pragma unroll
        for (int k4 = 0; k4 < 8; k4++) {
            float4 a4[8];
#pragma unroll
            for (int r = 0; r < 8; r++) {
                const int row = l0 + ty * 8 + r;
                a4[r] = *reinterpret_cast<const float4*>(
                    &y[((size_t)b * 4096 + row) * 192 + kb * 32 + k4 * 4]);
            }
            float4 w4[4];
#pragma unroll
            for (int c = 0; c < 4; c++)
                w4[c] = *reinterpret_cast<const float4*>(&Ws[tx * 4 + c][k4 * 4]);
#pragma unroll
            for (int r = 0; r < 8; r++)
#pragma unroll
                for (int c = 0; c < 4; c++) {
                    acc[r][c] = fmaf(a4[r].x, w4[c].x, acc[r][c]);
                    acc[r][c] = fmaf(a4[r].y, w4[c].y, acc[r][c]);
                    acc[r][c] = fmaf(a4[r].z, w4[c].z, acc[r][c]);
                    acc[r][c] = fmaf(a4[r].w, w4[c].w, acc[r][c]);
                }
        }
        __syncthreads();
    }
#pragma unroll
    for (int c = 0; c < 4; c++) {
        const int j = jb + tx * 4 + c;
        if (j < 96) {
            const int ch = 95 - j;
            const float4 v0 = make_float4(acc[0][c], acc[1][c], acc[2][c], acc[3][c]);
            const float4 v1 = make_float4(acc[4][c], acc[5][c], acc[6][c], acc[7][c]);
            const size_t base = ((size_t)b * 96 + ch) * 4096 + l0 + ty * 8;
            *reinterpret_cast<float4*>(&out[base]) = v0;
            *reinterpret_cast<float4*>(&out[base + 4]) = v1;
        }
    }
}

extern "C" void kernel_launch(void* const* d_in, const int* in_sizes, int n_in,
                              void* d_out, int out_size, void* d_ws, size_t ws_size,
                              hipStream_t stream)
{
    const float* x       = (const float*)d_in[0];
    const float* in_w    = (const float*)d_in[1];
    const float* conv_w  = (const float*)d_in[2];
    const float* conv_b  = (const float*)d_in[3];
    const float* xproj_w = (const float*)d_in[4];
    const float* dt_w    = (const float*)d_in[5];
    const float* dt_b    = (const float*)d_in[6];
    const float* A_log   = (const float*)d_in[7];
    const float* Dp      = (const float*)d_in[8];
    const float* out_w   = (const float*)d_in[9];

    // workspace layout (floats). total ~33.8M floats = 129 MB
    float* ws    = (float*)d_ws;
    float* u_raw = ws;                        // 6291456  (reused as y_final later)
    float* res   = u_raw + 6291456;           // 6291456
    float* u     = res   + 6291456;           // 6291456
    float* delta = u     + 6291456;           // 6291456
    float* dbc   = delta + 6291456;           // 1245184
    float* Barr  = dbc   + 1245184;           // 524288
    float* Carr  = Barr  + 524288;            // 524288
    float* P     = Carr  + 524288;            // 3145728
    float* S     = P     + 3145728;           // 3145728
    float* yfin  = u_raw;                     // alias: u_raw dead after conv

    hipLaunchKernelGGL(k_in_proj, dim3(32, 6, 8), dim3(256), 0, stream, x, in_w, u_raw, res);
    hipLaunchKernelGGL(k_conv,    dim3(4096, 8),  dim3(192), 0, stream, u_raw, conv_w, conv_b, u);
    hipLaunchKernelGGL(k_xproj,   dim3(32, 1, 8), dim3(256), 0, stream, u, xproj_w, dbc, Barr, Carr);
    hipLaunchKernelGGL(k_dtproj,  dim3(1024, 8),  dim3(192, 4), 0, stream, dbc, dt_w, dt_b, delta);
    hipLaunchKernelGGL(k_scan1,   dim3(NCHUNK, 8), dim3(192), 0, stream, delta, u, Barr, A_log, P, S);
    hipLaunchKernelGGL(k_scan2,   dim3(12, 8),    dim3(256), 0, stream, P, S);
    hipLaunchKernelGGL(k_scan3,   dim3(NCHUNK, 8), dim3(192), 0, stream, delta, u, Barr, Carr, A_log, S, Dp, res, yfin);
    hipLaunchKernelGGL(k_outproj, dim3(32, 2, 8), dim3(256), 0, stream, yfin, out_w, (float*)d_out);
}

// Round 3
// 280.436 us; speedup vs baseline: 1.6377x; 1.1267x over previous
//
#include <hip/hip_runtime.h>
#include <math.h>

// Problem constants (DRMamba): b=8, c=d_model=96, l=64*64=4096, d_inner=192,
// d_state=16, d_conv=4, dt_rank=6, REVERSE=True (channel flip folded into
// weight indexing on both ends).
#define NBATCH 8
#define SEQL   4096
#define DMODEL 96
#define DINNER 192
#define DSTATE 16
#define NDBC   38      // dt_rank + 2*d_state
#define NCHUNK 128
#define CSTEP  32      // NCHUNK*CSTEP == SEQL

__device__ __forceinline__ float siluf(float x) {
    return x / (1.f + expf(-x));
}
__device__ __forceinline__ float softplusf(float x) {
    return (x > 20.f) ? x : log1pf(expf(x));
}

// ---------------------------------------------------------------------------
// Kernel 1: in_proj GEMM.  out[b,l,j] = sum_m x[b,95-m,l] * w[j,m]
// j<192 -> u_raw, j>=192 -> res.  BM=128 (l), BN=64 (j), K=96 in 3 chunks of 32.
// Ws pad = 33: scalar read bank = (4*tx+c+k) mod 32 -> 2-way (free).
// ---------------------------------------------------------------------------
__global__ __launch_bounds__(256) void k_in_proj(const float* __restrict__ x,
                                                 const float* __restrict__ w,
                                                 float* __restrict__ u_raw,
                                                 float* __restrict__ res)
{
    __shared__ float As[32][128];
    __shared__ float Ws[64][33];
    const int tid = threadIdx.x;
    const int tx = tid & 15, ty = tid >> 4;
    const int b = blockIdx.z;
    const int l0 = blockIdx.x * 128;
    const int jb = blockIdx.y * 64;

    float acc[8][4];
#pragma unroll
    for (int r = 0; r < 8; r++)
#pragma unroll
        for (int c = 0; c < 4; c++) acc[r][c] = 0.f;

    for (int kb = 0; kb < 3; kb++) {
        // A tile: 32 m x 128 l, float4 loads along l (coalesced 512B/row-chunk)
        {
            const int ll4 = tid & 31;     // float4 column
            const int mb = tid >> 5;      // 0..7
#pragma unroll
            for (int i = 0; i < 4; i++) {
                const int m = mb + 8 * i;
                const float4 v = *reinterpret_cast<const float4*>(
                    &x[((size_t)b * 96 + (95 - (kb * 32 + m))) * 4096 + l0 + ll4 * 4]);
                *reinterpret_cast<float4*>(&As[m][ll4 * 4]) = v;
            }
        }
        // W tile: 64 j x 32 k, float4 global load, scalar LDS stores (pad 33)
        {
            const int k4 = tid & 7;
            const int jb0 = tid >> 3;     // 0..31
#pragma unroll
            for (int i = 0; i < 2; i++) {
                const int jl = jb0 + 32 * i;
                const float4 v = *reinterpret_cast<const float4*>(
                    &w[(size_t)(jb + jl) * 96 + kb * 32 + k4 * 4]);
                Ws[jl][k4 * 4 + 0] = v.x;
                Ws[jl][k4 * 4 + 1] = v.y;
                Ws[jl][k4 * 4 + 2] = v.z;
                Ws[jl][k4 * 4 + 3] = v.w;
            }
        }
        __syncthreads();
#pragma unroll
        for (int k = 0; k < 32; k++) {
            const float4 a0 = *reinterpret_cast<const float4*>(&As[k][ty * 8]);
            const float4 a1 = *reinterpret_cast<const float4*>(&As[k][ty * 8 + 4]);
            const float av[8] = {a0.x, a0.y, a0.z, a0.w, a1.x, a1.y, a1.z, a1.w};
            float wv[4];
#pragma unroll
            for (int c = 0; c < 4; c++) wv[c] = Ws[tx * 4 + c][k];
#pragma unroll
            for (int r = 0; r < 8; r++)
#pragma unroll
                for (int c = 0; c < 4; c++) acc[r][c] = fmaf(av[r], wv[c], acc[r][c]);
        }
        __syncthreads();
    }

    float* outp;
    int col0;
    if (jb < 192) { outp = u_raw; col0 = jb + tx * 4; }
    else          { outp = res;   col0 = jb - 192 + tx * 4; }
#pragma unroll
    for (int r = 0; r < 8; r++) {
        const int row = l0 + ty * 8 + r;
        const float4 v = make_float4(acc[r][0], acc[r][1], acc[r][2], acc[r][3]);
        *reinterpret_cast<float4*>(&outp[((size_t)b * 4096 + row) * 192 + col0]) = v;
    }
}

// ---------------------------------------------------------------------------
// Kernel 2: depthwise causal conv1d (k=4) + bias + silu. 4 t-steps/thread.
// ---------------------------------------------------------------------------
__global__ __launch_bounds__(192) void k_conv(const float* __restrict__ u_raw,
                                              const float* __restrict__ cw,
                                              const float* __restrict__ cb,
                                              float* __restrict__ u)
{
    const int d = threadIdx.x;
    const int t0 = blockIdx.x * 4;
    const int b = blockIdx.y;
    const float4 w4 = *reinterpret_cast<const float4*>(&cw[d * 4]);
    const float bias = cb[d];
    float v[7];
#pragma unroll
    for (int i = 0; i < 7; i++) {
        const int tt = t0 - 3 + i;
        v[i] = (tt >= 0) ? u_raw[((size_t)b * 4096 + tt) * 192 + d] : 0.f;
    }
#pragma unroll
    for (int j = 0; j < 4; j++) {
        float s = bias;
        s = fmaf(w4.x, v[j + 0], s);
        s = fmaf(w4.y, v[j + 1], s);
        s = fmaf(w4.z, v[j + 2], s);
        s = fmaf(w4.w, v[j + 3], s);
        u[((size_t)b * 4096 + t0 + j) * 192 + d] = siluf(s);
    }
}

// ---------------------------------------------------------------------------
// Kernel 3: x_proj GEMM.  dbc[j] = sum_k u[b,l,k] * w[j,k]  (j<38)
// j 0..5 -> dbc (for dt_proj), j 6..21 -> Barr, j 22..37 -> Carr.
// W tile XOR-swizzled: addr = j*32 + ((k4 ^ ((j>>2)&7))<<2) -> conflict-free.
// ---------------------------------------------------------------------------
__global__ __launch_bounds__(256) void k_xproj(const float* __restrict__ u,
                                               const float* __restrict__ w,
                                               float* __restrict__ dbc,
                                               float* __restrict__ Barr,
                                               float* __restrict__ Carr)
{
    __shared__ float Ws[64 * 32];
    const int tid = threadIdx.x, tx = tid & 15, ty = tid >> 4;
    const int b = blockIdx.z;
    const int l0 = blockIdx.x * 128;

    float acc[8][4];
#pragma unroll
    for (int r = 0; r < 8; r++)
#pragma unroll
        for (int c = 0; c < 4; c++) acc[r][c] = 0.f;

    for (int kb = 0; kb < 6; kb++) {
        {
            const int k4 = tid & 7;
            const int jb0 = tid >> 3;
#pragma unroll
            for (int i = 0; i < 2; i++) {
                const int jl = jb0 + 32 * i;
                float4 v = make_float4(0.f, 0.f, 0.f, 0.f);
                if (jl < NDBC)
                    v = *reinterpret_cast<const float4*>(&w[(size_t)jl * 192 + kb * 32 + k4 * 4]);
                *reinterpret_cast<float4*>(
                    &Ws[jl * 32 + ((k4 ^ ((jl >> 2) & 7)) << 2)]) = v;
            }
        }
        __syncthreads();
        const int sw = tx & 7;
#pragma unroll
        for (int k4 = 0; k4 < 8; k4++) {
            float4 a4[8];
#pragma unroll
            for (int r = 0; r < 8; r++) {
                const int row = l0 + ty * 8 + r;
                a4[r] = *reinterpret_cast<const float4*>(
                    &u[((size_t)b * 4096 + row) * 192 + kb * 32 + k4 * 4]);
            }
            float4 w4[4];
#pragma unroll
            for (int c = 0; c < 4; c++)
                w4[c] = *reinterpret_cast<const float4*>(
                    &Ws[(tx * 4 + c) * 32 + ((k4 ^ sw) << 2)]);
#pragma unroll
            for (int r = 0; r < 8; r++)
#pragma unroll
                for (int c = 0; c < 4; c++) {
                    acc[r][c] = fmaf(a4[r].x, w4[c].x, acc[r][c]);
                    acc[r][c] = fmaf(a4[r].y, w4[c].y, acc[r][c]);
                    acc[r][c] = fmaf(a4[r].z, w4[c].z, acc[r][c]);
                    acc[r][c] = fmaf(a4[r].w, w4[c].w, acc[r][c]);
                }
        }
        __syncthreads();
    }
#pragma unroll
    for (int r = 0; r < 8; r++) {
        const size_t row = (size_t)blockIdx.z * 4096 + l0 + ty * 8 + r;
#pragma unroll
        for (int c = 0; c < 4; c++) {
            const int j = tx * 4 + c;
            if (j < 6)       dbc[row * NDBC + j] = acc[r][c];
            else if (j < 22) Barr[row * 16 + (j - 6)] = acc[r][c];
            else if (j < 38) Carr[row * 16 + (j - 22)] = acc[r][c];
        }
    }
}

// ---------------------------------------------------------------------------
// Kernel 4: delta = softplus(dt @ dt_proj_w.T + dt_proj_b), K=6
// ---------------------------------------------------------------------------
__global__ __launch_bounds__(768) void k_dtproj(const float* __restrict__ dbc,
                                                const float* __restrict__ w,
                                                const float* __restrict__ bias,
                                                float* __restrict__ delta)
{
    const int j = threadIdx.x;                 // 0..191
    const int row = blockIdx.x * 4 + threadIdx.y;
    const int b = blockIdx.y;
    const size_t g = (size_t)b * 4096 + row;
    const float* dr = &dbc[g * NDBC];
    float s = bias[j];
#pragma unroll
    for (int k = 0; k < 6; k++) s = fmaf(dr[k], w[j * 6 + k], s);
    delta[g * 192 + j] = softplusf(s);
}

// ---------------------------------------------------------------------------
// Scan phase 1: one thread per (b, d, chunk); all 16 n in registers.
// ---------------------------------------------------------------------------
__global__ __launch_bounds__(192) void k_scan1(const float* __restrict__ delta,
                                               const float* __restrict__ u,
                                               const float* __restrict__ Barr,
                                               const float* __restrict__ A_log,
                                               float* __restrict__ P,
                                               float* __restrict__ S)
{
    const int d = threadIdx.x;                 // 0..191
    const int c = blockIdx.x;                  // chunk
    const int b = blockIdx.y;

    float a[16];
    {
        const float4* al = reinterpret_cast<const float4*>(&A_log[d * 16]);
#pragma unroll
        for (int i = 0; i < 4; i++) {
            const float4 v = al[i];
            a[4 * i + 0] = -expf(v.x);
            a[4 * i + 1] = -expf(v.y);
            a[4 * i + 2] = -expf(v.z);
            a[4 * i + 3] = -expf(v.w);
        }
    }
    float st[16], p[16];
#pragma unroll
    for (int n = 0; n < 16; n++) { st[n] = 0.f; p[n] = 1.f; }

    const size_t g0 = (size_t)b * 4096 + (size_t)c * CSTEP;
    const float* dp = delta + g0 * 192 + d;
    const float* up = u + g0 * 192 + d;
    const float* bp = Barr + g0 * 16;

#pragma unroll 2
    for (int t = 0; t < CSTEP; t++) {
        const float dt = dp[t * 192];
        const float dtu = dt * up[t * 192];
        float Bv[16];
        {
            const float4* b4 = reinterpret_cast<const float4*>(bp + t * 16);
#pragma unroll
            for (int i = 0; i < 4; i++) {
                const float4 v = b4[i];
                Bv[4 * i + 0] = v.x; Bv[4 * i + 1] = v.y;
                Bv[4 * i + 2] = v.z; Bv[4 * i + 3] = v.w;
            }
        }
#pragma unroll
        for (int n = 0; n < 16; n++) {
            const float dA = __expf(dt * a[n]);
            p[n] *= dA;
            st[n] = fmaf(dA, st[n], dtu * Bv[n]);
        }
    }

    const size_t idx = (((size_t)b * NCHUNK + c) * 192 + d) * 16;
    float4* Pp = reinterpret_cast<float4*>(&P[idx]);
    float4* Sp = reinterpret_cast<float4*>(&S[idx]);
#pragma unroll
    for (int i = 0; i < 4; i++) {
        Pp[i] = make_float4(p[4 * i], p[4 * i + 1], p[4 * i + 2], p[4 * i + 3]);
        Sp[i] = make_float4(st[4 * i], st[4 * i + 1], st[4 * i + 2], st[4 * i + 3]);
    }
}

// ---------------------------------------------------------------------------
// Scan phase 2: sequential combine over chunks; S[c] overwritten with the
// init state for chunk c (carry BEFORE chunk c).
// ---------------------------------------------------------------------------
__global__ __launch_bounds__(256) void k_scan2(const float* __restrict__ P,
                                               float* __restrict__ S)
{
    const int dn = blockIdx.x * 256 + threadIdx.x;   // 0..3071
    const int b = blockIdx.y;
    float carry = 0.f;
    const size_t base = (size_t)b * NCHUNK * 3072 + dn;
#pragma unroll 8
    for (int c = 0; c < NCHUNK; c++) {
        const size_t idx = base + (size_t)c * 3072;
        const float p = P[idx];
        const float s = S[idx];
        S[idx] = carry;
        carry = fmaf(p, carry, s);
    }
}

// ---------------------------------------------------------------------------
// Scan phase 3: re-run recurrence from correct init; y reduced in-register
// over n; fused epilogue y = (y + u*D) * silu(res).
// ---------------------------------------------------------------------------
__global__ __launch_bounds__(192) void k_scan3(const float* __restrict__ delta,
                                               const float* __restrict__ u,
                                               const float* __restrict__ Barr,
                                               const float* __restrict__ Carr,
                                               const float* __restrict__ A_log,
                                               const float* __restrict__ S,
                                               const float* __restrict__ Dp,
                                               const float* __restrict__ res,
                                               float* __restrict__ y)
{
    const int d = threadIdx.x;
    const int c = blockIdx.x;
    const int b = blockIdx.y;

    float a[16];
    {
        const float4* al = reinterpret_cast<const float4*>(&A_log[d * 16]);
#pragma unroll
        for (int i = 0; i < 4; i++) {
            const float4 v = al[i];
            a[4 * i + 0] = -expf(v.x);
            a[4 * i + 1] = -expf(v.y);
            a[4 * i + 2] = -expf(v.z);
            a[4 * i + 3] = -expf(v.w);
        }
    }
    float st[16];
    {
        const float4* Sp = reinterpret_cast<const float4*>(
            &S[(((size_t)b * NCHUNK + c) * 192 + d) * 16]);
#pragma unroll
        for (int i = 0; i < 4; i++) {
            const float4 v = Sp[i];
            st[4 * i + 0] = v.x; st[4 * i + 1] = v.y;
            st[4 * i + 2] = v.z; st[4 * i + 3] = v.w;
        }
    }
    const float Dd = Dp[d];

    const size_t g0 = (size_t)b * 4096 + (size_t)c * CSTEP;
    const float* dp = delta + g0 * 192 + d;
    const float* up = u + g0 * 192 + d;
    const float* rp = res + g0 * 192 + d;
    float* yp = y + g0 * 192 + d;
    const float* bp = Barr + g0 * 16;
    const float* cp = Carr + g0 * 16;

#pragma unroll 2
    for (int t = 0; t < CSTEP; t++) {
        const float dt = dp[t * 192];
        const float ut = up[t * 192];
        const float dtu = dt * ut;
        float Bv[16], Cv[16];
        {
            const float4* b4 = reinterpret_cast<const float4*>(bp + t * 16);
            const float4* c4 = reinterpret_cast<const float4*>(cp + t * 16);
#pragma unroll
            for (int i = 0; i < 4; i++) {
                const float4 v = b4[i];
                Bv[4 * i + 0] = v.x; Bv[4 * i + 1] = v.y;
                Bv[4 * i + 2] = v.z; Bv[4 * i + 3] = v.w;
                const float4 w = c4[i];
                Cv[4 * i + 0] = w.x; Cv[4 * i + 1] = w.y;
                Cv[4 * i + 2] = w.z; Cv[4 * i + 3] = w.w;
            }
        }
        float yt = 0.f;
#pragma unroll
        for (int n = 0; n < 16; n++) {
            const float dA = __expf(dt * a[n]);
            st[n] = fmaf(dA, st[n], dtu * Bv[n]);
            yt = fmaf(st[n], Cv[n], yt);
        }
        const float r = rp[t * 192];
        const float sig = __builtin_amdgcn_rcpf(1.f + __expf(-r));
        yp[t * 192] = fmaf(ut, Dd, yt) * (r * sig);
    }
}

// ---------------------------------------------------------------------------
// Kernel 8: out_proj GEMM with output transpose + channel flip.
// d_out[b, 95-j, l] = sum_k y[b,l,k] * w[j,k].  Swizzled W tile.
// ---------------------------------------------------------------------------
__global__ __launch_bounds__(256) void k_outproj(const float* __restrict__ y,
                                                 const float* __restrict__ w,
                                                 float* __restrict__ out)
{
    __shared__ float Ws[64 * 32];
    const int tid = threadIdx.x, tx = tid & 15, ty = tid >> 4;
    const int b = blockIdx.z;
    const int l0 = blockIdx.x * 128;
    const int jb = blockIdx.y * 64;

    float acc[8][4];
#pragma unroll
    for (int r = 0; r < 8; r++)
#pragma unroll
        for (int c = 0; c < 4; c++) acc[r][c] = 0.f;

    for (int kb = 0; kb < 6; kb++) {
        {
            const int k4 = tid & 7;
            const int jb0 = tid >> 3;
#pragma unroll
            for (int i = 0; i < 2; i++) {
                const int jl = jb0 + 32 * i;
                const int j = jb + jl;
                float4 v = make_float4(0.f, 0.f, 0.f, 0.f);
                if (j < 96)
                    v = *reinterpret_cast<const float4*>(&w[(size_t)j * 192 + kb * 32 + k4 * 4]);
                *reinterpret_cast<float4*>(
                    &Ws[jl * 32 + ((k4 ^ ((jl >> 2) & 7)) << 2)]) = v;
            }
        }
        __syncthreads();
        const int sw = tx & 7;
#pragma unroll
        for (int k4 = 0; k4 < 8; k4++) {
            float4 a4[8];
#pragma unroll
            for (int r = 0; r < 8; r++) {
                const int row = l0 + ty * 8 + r;
                a4[r] = *reinterpret_cast<const float4*>(
                    &y[((size_t)b * 4096 + row) * 192 + kb * 32 + k4 * 4]);
            }
            float4 w4[4];
#pragma unroll
            for (int c = 0; c < 4; c++)
                w4[c] = *reinterpret_cast<const float4*>(
                    &Ws[(tx * 4 + c) * 32 + ((k4 ^ sw) << 2)]);
#pragma unroll
            for (int r = 0; r < 8; r++)
#pragma unroll
                for (int c = 0; c < 4; c++) {
                    acc[r][c] = fmaf(a4[r].x, w4[c].x, acc[r][c]);
                    acc[r][c] = fmaf(a4[r].y, w4[c].y, acc[r][c]);
                    acc[r][c] = fmaf(a4[r].z, w4[c].z, acc[r][c]);
                    acc[r][c] = fmaf(a4[r].w, w4[c].w, acc[r][c]);
                }
        }
        __syncthreads();
    }
#pragma unroll
    for (int c = 0; c < 4; c++) {
        const int j = jb + tx * 4 + c;
        if (j < 96) {
            const int ch = 95 - j;
            const float4 v0 = make_float4(acc[0][c], acc[1][c], acc[2][c], acc[3][c]);
            const float4 v1 = make_float4(acc[4][c], acc[5][c], acc[6][c], acc[7][c]);
            const size_t base = ((size_t)b * 96 + ch) * 4096 + l0 + ty * 8;
            *reinterpret_cast<float4*>(&out[base]) = v0;
            *reinterpret_cast<float4*>(&out[base + 4]) = v1;
        }
    }
}

extern "C" void kernel_launch(void* const* d_in, const int* in_sizes, int n_in,
                              void* d_out, int out_size, void* d_ws, size_t ws_size,
                              hipStream_t stream)
{
    const float* x       = (const float*)d_in[0];
    const float* in_w    = (const float*)d_in[1];
    const float* conv_w  = (const float*)d_in[2];
    const float* conv_b  = (const float*)d_in[3];
    const float* xproj_w = (const float*)d_in[4];
    const float* dt_w    = (const float*)d_in[5];
    const float* dt_b    = (const float*)d_in[6];
    const float* A_log   = (const float*)d_in[7];
    const float* Dp      = (const float*)d_in[8];
    const float* out_w   = (const float*)d_in[9];

    // workspace layout (floats). total ~33.8M floats = 129 MB
    float* ws    = (float*)d_ws;
    float* u_raw = ws;                        // 6291456  (reused as y_final later)
    float* res   = u_raw + 6291456;           // 6291456
    float* u     = res   + 6291456;           // 6291456
    float* delta = u     + 6291456;           // 6291456
    float* dbc   = delta + 6291456;           // 1245184
    float* Barr  = dbc   + 1245184;           // 524288
    float* Carr  = Barr  + 524288;            // 524288
    float* P     = Carr  + 524288;            // 3145728
    float* S     = P     + 3145728;           // 3145728
    float* yfin  = u_raw;                     // alias: u_raw dead after conv

    hipLaunchKernelGGL(k_in_proj, dim3(32, 6, 8), dim3(256), 0, stream, x, in_w, u_raw, res);
    hipLaunchKernelGGL(k_conv,    dim3(1024, 8),  dim3(192), 0, stream, u_raw, conv_w, conv_b, u);
    hipLaunchKernelGGL(k_xproj,   dim3(32, 1, 8), dim3(256), 0, stream, u, xproj_w, dbc, Barr, Carr);
    hipLaunchKernelGGL(k_dtproj,  dim3(1024, 8),  dim3(192, 4), 0, stream, dbc, dt_w, dt_b, delta);
    hipLaunchKernelGGL(k_scan1,   dim3(NCHUNK, 8), dim3(192), 0, stream, delta, u, Barr, A_log, P, S);
    hipLaunchKernelGGL(k_scan2,   dim3(12, 8),    dim3(256), 0, stream, P, S);
    hipLaunchKernelGGL(k_scan3,   dim3(NCHUNK, 8), dim3(192), 0, stream, delta, u, Barr, Carr, A_log, S, Dp, res, yfin);
    hipLaunchKernelGGL(k_outproj, dim3(32, 2, 8), dim3(256), 0, stream, yfin, out_w, (float*)d_out);
}

// Round 4
// 279.969 us; speedup vs baseline: 1.6405x; 1.0017x over previous
//
#include <hip/hip_runtime.h>
#include <math.h>

// Problem constants (DRMamba): b=8, c=d_model=96, l=64*64=4096, d_inner=192,
// d_state=16, d_conv=4, dt_rank=6, REVERSE=True (channel flip folded into
// weight indexing on both ends).
#define NBATCH 8
#define SEQL   4096
#define DMODEL 96
#define DINNER 192
#define DSTATE 16
#define NDBC   38      // dt_rank + 2*d_state
#define NCHUNK 128
#define CSTEP  32      // NCHUNK*CSTEP == SEQL

__device__ __forceinline__ float siluf(float x) {
    return x / (1.f + expf(-x));
}
__device__ __forceinline__ float softplusf(float x) {
    return (x > 20.f) ? x : log1pf(expf(x));
}

// ---------------------------------------------------------------------------
// Kernel 1: in_proj GEMM.  out[b,l,j] = sum_m x[b,95-m,l] * w[j,m]
// j<192 -> u_raw, j>=192 -> res.
// 128 threads, BM=128 (l), BN=64 (j), 8x8 register tile, K=96 in 3 chunks.
// A kept K-major in As[32][128]; W transposed into Wt[32][68] so both frag
// reads are b128 (2-way bank aliasing max = free).
// ---------------------------------------------------------------------------
__global__ __launch_bounds__(128) void k_in_proj(const float* __restrict__ x,
                                                 const float* __restrict__ w,
                                                 float* __restrict__ u_raw,
                                                 float* __restrict__ res)
{
    __shared__ float As[32][128];   // 16 KB
    __shared__ float Wt[32][68];    // 8.5 KB, [k][j] transposed
    const int tid = threadIdx.x;
    const int jg = tid & 7;         // j-group: 8 cols each
    const int lg = tid >> 3;        // l-group 0..15: 8 rows each
    const int b = blockIdx.z;
    const int l0 = blockIdx.x * 128;
    const int jb = blockIdx.y * 64;

    float acc[8][8];
#pragma unroll
    for (int r = 0; r < 8; r++)
#pragma unroll
        for (int c = 0; c < 8; c++) acc[r][c] = 0.f;

    for (int kb = 0; kb < 3; kb++) {
        // A tile: 32 m x 128 l, float4 along l. 8 f4/thread.
        {
            const int ll4 = tid & 31;     // f4 column 0..31
            const int m0 = tid >> 5;      // 0..3
#pragma unroll
            for (int i = 0; i < 8; i++) {
                const int m = m0 + 4 * i;
                const float4 v = *reinterpret_cast<const float4*>(
                    &x[((size_t)b * 96 + (95 - (kb * 32 + m))) * 4096 + l0 + ll4 * 4]);
                *reinterpret_cast<float4*>(&As[m][ll4 * 4]) = v;
            }
        }
        // W tile: transpose 64 j x 32 k into Wt[k][j]. 4 f4/thread.
        {
            const int k4 = tid & 7;
            const int jl0 = tid >> 3;     // 0..15
#pragma unroll
            for (int i = 0; i < 4; i++) {
                const int jl = jl0 + 16 * i;
                const float4 v = *reinterpret_cast<const float4*>(
                    &w[(size_t)(jb + jl) * 96 + kb * 32 + k4 * 4]);
                Wt[k4 * 4 + 0][jl] = v.x;
                Wt[k4 * 4 + 1][jl] = v.y;
                Wt[k4 * 4 + 2][jl] = v.z;
                Wt[k4 * 4 + 3][jl] = v.w;
            }
        }
        __syncthreads();
#pragma unroll
        for (int k = 0; k < 32; k++) {
            const float4 a0 = *reinterpret_cast<const float4*>(&As[k][lg * 8]);
            const float4 a1 = *reinterpret_cast<const float4*>(&As[k][lg * 8 + 4]);
            const float4 w0 = *reinterpret_cast<const float4*>(&Wt[k][jg * 8]);
            const float4 w1 = *reinterpret_cast<const float4*>(&Wt[k][jg * 8 + 4]);
            const float av[8] = {a0.x, a0.y, a0.z, a0.w, a1.x, a1.y, a1.z, a1.w};
            const float wv[8] = {w0.x, w0.y, w0.z, w0.w, w1.x, w1.y, w1.z, w1.w};
#pragma unroll
            for (int r = 0; r < 8; r++)
#pragma unroll
                for (int c = 0; c < 8; c++) acc[r][c] = fmaf(av[r], wv[c], acc[r][c]);
        }
        __syncthreads();
    }

    float* outp;
    int col0;
    if (jb < 192) { outp = u_raw; col0 = jb + jg * 8; }
    else          { outp = res;   col0 = jb - 192 + jg * 8; }
#pragma unroll
    for (int r = 0; r < 8; r++) {
        const int row = l0 + lg * 8 + r;
        float* rowp = &outp[((size_t)b * 4096 + row) * 192 + col0];
        *reinterpret_cast<float4*>(rowp) =
            make_float4(acc[r][0], acc[r][1], acc[r][2], acc[r][3]);
        *reinterpret_cast<float4*>(rowp + 4) =
            make_float4(acc[r][4], acc[r][5], acc[r][6], acc[r][7]);
    }
}

// ---------------------------------------------------------------------------
// Kernel 3 (fused): depthwise causal conv1d(4)+bias+silu  ->  u (global)
//                   + x_proj GEMM  dbc[j] = sum_k u[b,l,k] * w[j,k]  (j<38)
// BM=64 rows, K=192 in 6 chunks of 32 channels. Per chunk: stage u_raw rows
// l0-3..l0+63 in LDS, conv+silu into Us, write u back, GEMM from Us.
// j 0..5 -> dbc, j 6..21 -> Barr, j 22..37 -> Carr.
// ---------------------------------------------------------------------------
__global__ __launch_bounds__(256) void k_xproj(const float* __restrict__ u_raw,
                                               const float* __restrict__ w,
                                               const float* __restrict__ cw,
                                               const float* __restrict__ cb,
                                               float* __restrict__ u,
                                               float* __restrict__ dbc,
                                               float* __restrict__ Barr,
                                               float* __restrict__ Carr)
{
    __shared__ float Ur[67][33];    // u_raw rows l0-3 .. l0+63 (halo), 8.8 KB
    __shared__ float Us[64][36];    // conv output (=u tile), b128-aligned pitch
    __shared__ float Ws[64 * 32];   // XOR-swizzled weights
    const int tid = threadIdx.x, tx = tid & 15, ty = tid >> 4;
    const int b = blockIdx.y;
    const int l0 = blockIdx.x * 64;

    float acc[4][4];
#pragma unroll
    for (int r = 0; r < 4; r++)
#pragma unroll
        for (int c = 0; c < 4; c++) acc[r][c] = 0.f;

    const int ch = tid & 31;        // conv channel within chunk
    const int lblk = tid >> 5;      // 0..7: 8 l-rows each

    for (int kb = 0; kb < 6; kb++) {
        // ---- stage Ur: 67 rows x 32 chans (8 f4-cols per row), 536 f4 total
        for (int idx = tid; idx < 536; idx += 256) {
            const int row = idx >> 3;
            const int c4 = idx & 7;
            const int gl = l0 - 3 + row;
            float4 v = make_float4(0.f, 0.f, 0.f, 0.f);
            if (gl >= 0)
                v = *reinterpret_cast<const float4*>(
                    &u_raw[((size_t)b * 4096 + gl) * 192 + kb * 32 + c4 * 4]);
            Ur[row][c4 * 4 + 0] = v.x;
            Ur[row][c4 * 4 + 1] = v.y;
            Ur[row][c4 * 4 + 2] = v.z;
            Ur[row][c4 * 4 + 3] = v.w;
        }
        // ---- stage Ws (swizzled), j<38 guard
        {
            const int k4 = tid & 7;
            const int jb0 = tid >> 3;
#pragma unroll
            for (int i = 0; i < 2; i++) {
                const int jl = jb0 + 32 * i;
                float4 v = make_float4(0.f, 0.f, 0.f, 0.f);
                if (jl < NDBC)
                    v = *reinterpret_cast<const float4*>(&w[(size_t)jl * 192 + kb * 32 + k4 * 4]);
                *reinterpret_cast<float4*>(
                    &Ws[jl * 32 + ((k4 ^ ((jl >> 2) & 7)) << 2)]) = v;
            }
        }
        __syncthreads();

        // ---- conv + silu: each thread does 8 rows of one channel
        {
            const float4 wc = *reinterpret_cast<const float4*>(&cw[(kb * 32 + ch) * 4]);
            const float bias = cb[kb * 32 + ch];
#pragma unroll
            for (int r = 0; r < 8; r++) {
                const int l = lblk * 8 + r;
                float s = bias;
                s = fmaf(wc.x, Ur[l + 0][ch], s);
                s = fmaf(wc.y, Ur[l + 1][ch], s);
                s = fmaf(wc.z, Ur[l + 2][ch], s);
                s = fmaf(wc.w, Ur[l + 3][ch], s);
                Us[l][ch] = siluf(s);
            }
        }
        __syncthreads();

        // ---- write u tile back to global (scans need it)
        for (int idx = tid; idx < 512; idx += 256) {
            const int row = idx >> 3;
            const int c4 = idx & 7;
            const float4 v = *reinterpret_cast<const float4*>(&Us[row][c4 * 4]);
            *reinterpret_cast<float4*>(
                &u[((size_t)b * 4096 + l0 + row) * 192 + kb * 32 + c4 * 4]) = v;
        }

        // ---- GEMM inner loop: A from Us, W from Ws
        const int sw = tx & 7;
#pragma unroll
        for (int k4 = 0; k4 < 8; k4++) {
            float4 a4[4];
#pragma unroll
            for (int r = 0; r < 4; r++)
                a4[r] = *reinterpret_cast<const float4*>(&Us[ty * 4 + r][k4 * 4]);
            float4 w4[4];
#pragma unroll
            for (int c = 0; c < 4; c++)
                w4[c] = *reinterpret_cast<const float4*>(
                    &Ws[(tx * 4 + c) * 32 + ((k4 ^ sw) << 2)]);
#pragma unroll
            for (int r = 0; r < 4; r++)
#pragma unroll
                for (int c = 0; c < 4; c++) {
                    acc[r][c] = fmaf(a4[r].x, w4[c].x, acc[r][c]);
                    acc[r][c] = fmaf(a4[r].y, w4[c].y, acc[r][c]);
                    acc[r][c] = fmaf(a4[r].z, w4[c].z, acc[r][c]);
                    acc[r][c] = fmaf(a4[r].w, w4[c].w, acc[r][c]);
                }
        }
        __syncthreads();
    }

#pragma unroll
    for (int r = 0; r < 4; r++) {
        const size_t row = (size_t)b * 4096 + l0 + ty * 4 + r;
#pragma unroll
        for (int c = 0; c < 4; c++) {
            const int j = tx * 4 + c;
            if (j < 6)       dbc[row * NDBC + j] = acc[r][c];
            else if (j < 22) Barr[row * 16 + (j - 6)] = acc[r][c];
            else if (j < 38) Carr[row * 16 + (j - 22)] = acc[r][c];
        }
    }
}

// ---------------------------------------------------------------------------
// Kernel 4: delta = softplus(dt @ dt_proj_w.T + dt_proj_b), K=6
// ---------------------------------------------------------------------------
__global__ __launch_bounds__(768) void k_dtproj(const float* __restrict__ dbc,
                                                const float* __restrict__ w,
                                                const float* __restrict__ bias,
                                                float* __restrict__ delta)
{
    const int j = threadIdx.x;                 // 0..191
    const int row = blockIdx.x * 4 + threadIdx.y;
    const int b = blockIdx.y;
    const size_t g = (size_t)b * 4096 + row;
    const float* dr = &dbc[g * NDBC];
    float s = bias[j];
#pragma unroll
    for (int k = 0; k < 6; k++) s = fmaf(dr[k], w[j * 6 + k], s);
    delta[g * 192 + j] = softplusf(s);
}

// ---------------------------------------------------------------------------
// Scan phase 1: one thread per (b, d, chunk); all 16 n in registers.
// ---------------------------------------------------------------------------
__global__ __launch_bounds__(192) void k_scan1(const float* __restrict__ delta,
                                               const float* __restrict__ u,
                                               const float* __restrict__ Barr,
                                               const float* __restrict__ A_log,
                                               float* __restrict__ P,
                                               float* __restrict__ S)
{
    const int d = threadIdx.x;                 // 0..191
    const int c = blockIdx.x;                  // chunk
    const int b = blockIdx.y;

    float a[16];
    {
        const float4* al = reinterpret_cast<const float4*>(&A_log[d * 16]);
#pragma unroll
        for (int i = 0; i < 4; i++) {
            const float4 v = al[i];
            a[4 * i + 0] = -expf(v.x);
            a[4 * i + 1] = -expf(v.y);
            a[4 * i + 2] = -expf(v.z);
            a[4 * i + 3] = -expf(v.w);
        }
    }
    float st[16], p[16];
#pragma unroll
    for (int n = 0; n < 16; n++) { st[n] = 0.f; p[n] = 1.f; }

    const size_t g0 = (size_t)b * 4096 + (size_t)c * CSTEP;
    const float* dp = delta + g0 * 192 + d;
    const float* up = u + g0 * 192 + d;
    const float* bp = Barr + g0 * 16;

#pragma unroll 2
    for (int t = 0; t < CSTEP; t++) {
        const float dt = dp[t * 192];
        const float dtu = dt * up[t * 192];
        float Bv[16];
        {
            const float4* b4 = reinterpret_cast<const float4*>(bp + t * 16);
#pragma unroll
            for (int i = 0; i < 4; i++) {
                const float4 v = b4[i];
                Bv[4 * i + 0] = v.x; Bv[4 * i + 1] = v.y;
                Bv[4 * i + 2] = v.z; Bv[4 * i + 3] = v.w;
            }
        }
#pragma unroll
        for (int n = 0; n < 16; n++) {
            const float dA = __expf(dt * a[n]);
            p[n] *= dA;
            st[n] = fmaf(dA, st[n], dtu * Bv[n]);
        }
    }

    const size_t idx = (((size_t)b * NCHUNK + c) * 192 + d) * 16;
    float4* Pp = reinterpret_cast<float4*>(&P[idx]);
    float4* Sp = reinterpret_cast<float4*>(&S[idx]);
#pragma unroll
    for (int i = 0; i < 4; i++) {
        Pp[i] = make_float4(p[4 * i], p[4 * i + 1], p[4 * i + 2], p[4 * i + 3]);
        Sp[i] = make_float4(st[4 * i], st[4 * i + 1], st[4 * i + 2], st[4 * i + 3]);
    }
}

// ---------------------------------------------------------------------------
// Scan phase 2: sequential combine over chunks; S[c] overwritten with the
// init state for chunk c (carry BEFORE chunk c).
// ---------------------------------------------------------------------------
__global__ __launch_bounds__(256) void k_scan2(const float* __restrict__ P,
                                               float* __restrict__ S)
{
    const int dn = blockIdx.x * 256 + threadIdx.x;   // 0..3071
    const int b = blockIdx.y;
    float carry = 0.f;
    const size_t base = (size_t)b * NCHUNK * 3072 + dn;
#pragma unroll 8
    for (int c = 0; c < NCHUNK; c++) {
        const size_t idx = base + (size_t)c * 3072;
        const float p = P[idx];
        const float s = S[idx];
        S[idx] = carry;
        carry = fmaf(p, carry, s);
    }
}

// ---------------------------------------------------------------------------
// Scan phase 3: re-run recurrence from correct init; y reduced in-register
// over n; fused epilogue y = (y + u*D) * silu(res).
// ---------------------------------------------------------------------------
__global__ __launch_bounds__(192) void k_scan3(const float* __restrict__ delta,
                                               const float* __restrict__ u,
                                               const float* __restrict__ Barr,
                                               const float* __restrict__ Carr,
                                               const float* __restrict__ A_log,
                                               const float* __restrict__ S,
                                               const float* __restrict__ Dp,
                                               const float* __restrict__ res,
                                               float* __restrict__ y)
{
    const int d = threadIdx.x;
    const int c = blockIdx.x;
    const int b = blockIdx.y;

    float a[16];
    {
        const float4* al = reinterpret_cast<const float4*>(&A_log[d * 16]);
#pragma unroll
        for (int i = 0; i < 4; i++) {
            const float4 v = al[i];
            a[4 * i + 0] = -expf(v.x);
            a[4 * i + 1] = -expf(v.y);
            a[4 * i + 2] = -expf(v.z);
            a[4 * i + 3] = -expf(v.w);
        }
    }
    float st[16];
    {
        const float4* Sp = reinterpret_cast<const float4*>(
            &S[(((size_t)b * NCHUNK + c) * 192 + d) * 16]);
#pragma unroll
        for (int i = 0; i < 4; i++) {
            const float4 v = Sp[i];
            st[4 * i + 0] = v.x; st[4 * i + 1] = v.y;
            st[4 * i + 2] = v.z; st[4 * i + 3] = v.w;
        }
    }
    const float Dd = Dp[d];

    const size_t g0 = (size_t)b * 4096 + (size_t)c * CSTEP;
    const float* dp = delta + g0 * 192 + d;
    const float* up = u + g0 * 192 + d;
    const float* rp = res + g0 * 192 + d;
    float* yp = y + g0 * 192 + d;
    const float* bp = Barr + g0 * 16;
    const float* cp = Carr + g0 * 16;

#pragma unroll 2
    for (int t = 0; t < CSTEP; t++) {
        const float dt = dp[t * 192];
        const float ut = up[t * 192];
        const float dtu = dt * ut;
        float Bv[16], Cv[16];
        {
            const float4* b4 = reinterpret_cast<const float4*>(bp + t * 16);
            const float4* c4 = reinterpret_cast<const float4*>(cp + t * 16);
#pragma unroll
            for (int i = 0; i < 4; i++) {
                const float4 v = b4[i];
                Bv[4 * i + 0] = v.x; Bv[4 * i + 1] = v.y;
                Bv[4 * i + 2] = v.z; Bv[4 * i + 3] = v.w;
                const float4 w = c4[i];
                Cv[4 * i + 0] = w.x; Cv[4 * i + 1] = w.y;
                Cv[4 * i + 2] = w.z; Cv[4 * i + 3] = w.w;
            }
        }
        float yt = 0.f;
#pragma unroll
        for (int n = 0; n < 16; n++) {
            const float dA = __expf(dt * a[n]);
            st[n] = fmaf(dA, st[n], dtu * Bv[n]);
            yt = fmaf(st[n], Cv[n], yt);
        }
        const float r = rp[t * 192];
        const float sig = __builtin_amdgcn_rcpf(1.f + __expf(-r));
        yp[t * 192] = fmaf(ut, Dd, yt) * (r * sig);
    }
}

// ---------------------------------------------------------------------------
// Kernel 8: out_proj GEMM with output transpose + channel flip.
// d_out[b, 95-j, l] = sum_k y[b,l,k] * w[j,k].  Swizzled W tile.
// ---------------------------------------------------------------------------
__global__ __launch_bounds__(256) void k_outproj(const float* __restrict__ y,
                                                 const float* __restrict__ w,
                                                 float* __restrict__ out)
{
    __shared__ float Ws[64 * 32];
    const int tid = threadIdx.x, tx = tid & 15, ty = tid >> 4;
    const int b = blockIdx.z;
    const int l0 = blockIdx.x * 128;
    const int jb = blockIdx.y * 64;

    float acc[8][4];
#pragma unroll
    for (int r = 0; r < 8; r++)
#pragma unroll
        for (int c = 0; c < 4; c++) acc[r][c] = 0.f;

    for (int kb = 0; kb < 6; kb++) {
        {
            const int k4 = tid & 7;
            const int jb0 = tid >> 3;
#pragma unroll
            for (int i = 0; i < 2; i++) {
                const int jl = jb0 + 32 * i;
                const int j = jb + jl;
                float4 v = make_float4(0.f, 0.f, 0.f, 0.f);
                if (j < 96)
                    v = *reinterpret_cast<const float4*>(&w[(size_t)j * 192 + kb * 32 + k4 * 4]);
                *reinterpret_cast<float4*>(
                    &Ws[jl * 32 + ((k4 ^ ((jl >> 2) & 7)) << 2)]) = v;
            }
        }
        __syncthreads();
        const int sw = tx & 7;
#pragma unroll
        for (int k4 = 0; k4 < 8; k4++) {
            float4 a4[8];
#pragma unroll
            for (int r = 0; r < 8; r++) {
                const int row = l0 + ty * 8 + r;
                a4[r] = *reinterpret_cast<const float4*>(
                    &y[((size_t)b * 4096 + row) * 192 + kb * 32 + k4 * 4]);
            }
            float4 w4[4];
#pragma unroll
            for (int c = 0; c < 4; c++)
                w4[c] = *reinterpret_cast<const float4*>(
                    &Ws[(tx * 4 + c) * 32 + ((k4 ^ sw) << 2)]);
#pragma unroll
            for (int r = 0; r < 8; r++)
#pragma unroll
                for (int c = 0; c < 4; c++) {
                    acc[r][c] = fmaf(a4[r].x, w4[c].x, acc[r][c]);
                    acc[r][c] = fmaf(a4[r].y, w4[c].y, acc[r][c]);
                    acc[r][c] = fmaf(a4[r].z, w4[c].z, acc[r][c]);
                    acc[r][c] = fmaf(a4[r].w, w4[c].w, acc[r][c]);
                }
        }
        __syncthreads();
    }
#pragma unroll
    for (int c = 0; c < 4; c++) {
        const int j = jb + tx * 4 + c;
        if (j < 96) {
            const int ch = 95 - j;
            const float4 v0 = make_float4(acc[0][c], acc[1][c], acc[2][c], acc[3][c]);
            const float4 v1 = make_float4(acc[4][c], acc[5][c], acc[6][c], acc[7][c]);
            const size_t base = ((size_t)b * 96 + ch) * 4096 + l0 + ty * 8;
            *reinterpret_cast<float4*>(&out[base]) = v0;
            *reinterpret_cast<float4*>(&out[base + 4]) = v1;
        }
    }
}

extern "C" void kernel_launch(void* const* d_in, const int* in_sizes, int n_in,
                              void* d_out, int out_size, void* d_ws, size_t ws_size,
                              hipStream_t stream)
{
    const float* x       = (const float*)d_in[0];
    const float* in_w    = (const float*)d_in[1];
    const float* conv_w  = (const float*)d_in[2];
    const float* conv_b  = (const float*)d_in[3];
    const float* xproj_w = (const float*)d_in[4];
    const float* dt_w    = (const float*)d_in[5];
    const float* dt_b    = (const float*)d_in[6];
    const float* A_log   = (const float*)d_in[7];
    const float* Dp      = (const float*)d_in[8];
    const float* out_w   = (const float*)d_in[9];

    // workspace layout (floats). total ~33.8M floats = 129 MB
    float* ws    = (float*)d_ws;
    float* u_raw = ws;                        // 6291456  (reused as y_final later)
    float* res   = u_raw + 6291456;           // 6291456
    float* u     = res   + 6291456;           // 6291456
    float* delta = u     + 6291456;           // 6291456
    float* dbc   = delta + 6291456;           // 1245184
    float* Barr  = dbc   + 1245184;           // 524288
    float* Carr  = Barr  + 524288;            // 524288
    float* P     = Carr  + 524288;            // 3145728
    float* S     = P     + 3145728;           // 3145728
    float* yfin  = u_raw;                     // alias: u_raw dead after xproj

    hipLaunchKernelGGL(k_in_proj, dim3(32, 6, 8), dim3(128), 0, stream, x, in_w, u_raw, res);
    hipLaunchKernelGGL(k_xproj,   dim3(64, 8),    dim3(256), 0, stream,
                       u_raw, xproj_w, conv_w, conv_b, u, dbc, Barr, Carr);
    hipLaunchKernelGGL(k_dtproj,  dim3(1024, 8),  dim3(192, 4), 0, stream, dbc, dt_w, dt_b, delta);
    hipLaunchKernelGGL(k_scan1,   dim3(NCHUNK, 8), dim3(192), 0, stream, delta, u, Barr, A_log, P, S);
    hipLaunchKernelGGL(k_scan2,   dim3(12, 8),    dim3(256), 0, stream, P, S);
    hipLaunchKernelGGL(k_scan3,   dim3(NCHUNK, 8), dim3(192), 0, stream, delta, u, Barr, Carr, A_log, S, Dp, res, yfin);
    hipLaunchKernelGGL(k_outproj, dim3(32, 2, 8), dim3(256), 0, stream, yfin, out_w, (float*)d_out);
}

// Round 5
// 274.037 us; speedup vs baseline: 1.6760x; 1.0216x over previous
//
#include <hip/hip_runtime.h>
#include <math.h>

// Problem constants (DRMamba): b=8, c=d_model=96, l=64*64=4096, d_inner=192,
// d_state=16, d_conv=4, dt_rank=6, REVERSE=True (channel flip folded into
// weight indexing on both ends).
#define NBATCH 8
#define SEQL   4096
#define DMODEL 96
#define DINNER 192
#define DSTATE 16
#define NDBC   38      // dt_rank + 2*d_state
#define NCHUNK 128
#define CSTEP  32      // NCHUNK*CSTEP == SEQL

__device__ __forceinline__ float siluf(float x) {
    return x / (1.f + expf(-x));
}
__device__ __forceinline__ float silu_fast(float x) {
    return x * __builtin_amdgcn_rcpf(1.f + __expf(-x));
}
__device__ __forceinline__ float softplus_fast(float x) {
    return (x > 15.f) ? x : __logf(1.f + __expf(x));
}

// ---------------------------------------------------------------------------
// Kernel 1: in_proj GEMM.  out[b,l,j] = sum_m x[b,95-m,l] * w[j,m]
// j<192 -> u_raw, j>=192 -> res.
// 256 threads, BM=128 (l), BN=128 (j), 8x8 register tile, K=96 in 3 chunks.
// Per k-iter: 4 ds_read_b128 -> 64 FMA (LDS port and VALU balanced).
// Wt pad 133: transpose-stores and frag reads both <=2-way bank aliasing.
// 33 KB LDS -> 4 blocks/CU -> 16 waves/CU capacity, grid gives 12.
// ---------------------------------------------------------------------------
__global__ __launch_bounds__(256) void k_in_proj(const float* __restrict__ x,
                                                 const float* __restrict__ w,
                                                 float* __restrict__ u_raw,
                                                 float* __restrict__ res)
{
    __shared__ float As[32][128];   // 16 KB, [k][l]
    __shared__ float Wt[32][133];   // 17 KB, [k][j] transposed
    const int tid = threadIdx.x;
    const int jg = tid & 15;        // j-group: 8 cols each
    const int lg = tid >> 4;        // l-group: 8 rows each
    const int b = blockIdx.z;
    const int l0 = blockIdx.x * 128;
    const int jb = blockIdx.y * 128;

    float acc[8][8];
#pragma unroll
    for (int r = 0; r < 8; r++)
#pragma unroll
        for (int c = 0; c < 8; c++) acc[r][c] = 0.f;

    for (int kb = 0; kb < 3; kb++) {
        // A tile: 32 m x 128 l, float4 along l. 4 f4/thread.
        {
            const int ll4 = tid & 31;     // f4 column 0..31
            const int m0 = tid >> 5;      // 0..7
#pragma unroll
            for (int i = 0; i < 4; i++) {
                const int m = m0 + 8 * i;
                const float4 v = *reinterpret_cast<const float4*>(
                    &x[((size_t)b * 96 + (95 - (kb * 32 + m))) * 4096 + l0 + ll4 * 4]);
                *reinterpret_cast<float4*>(&As[m][ll4 * 4]) = v;
            }
        }
        // W tile: transpose 128 j x 32 k into Wt[k][j]. 4 f4/thread.
        {
            const int k4 = tid & 7;
            const int jl0 = tid >> 3;     // 0..31
#pragma unroll
            for (int i = 0; i < 4; i++) {
                const int jl = jl0 + 32 * i;
                const float4 v = *reinterpret_cast<const float4*>(
                    &w[(size_t)(jb + jl) * 96 + kb * 32 + k4 * 4]);
                Wt[k4 * 4 + 0][jl] = v.x;
                Wt[k4 * 4 + 1][jl] = v.y;
                Wt[k4 * 4 + 2][jl] = v.z;
                Wt[k4 * 4 + 3][jl] = v.w;
            }
        }
        __syncthreads();
#pragma unroll
        for (int k = 0; k < 32; k++) {
            const float4 a0 = *reinterpret_cast<const float4*>(&As[k][lg * 8]);
            const float4 a1 = *reinterpret_cast<const float4*>(&As[k][lg * 8 + 4]);
            const float4 w0 = *reinterpret_cast<const float4*>(&Wt[k][jg * 8]);
            const float4 w1 = *reinterpret_cast<const float4*>(&Wt[k][jg * 8 + 4]);
            const float av[8] = {a0.x, a0.y, a0.z, a0.w, a1.x, a1.y, a1.z, a1.w};
            const float wv[8] = {w0.x, w0.y, w0.z, w0.w, w1.x, w1.y, w1.z, w1.w};
#pragma unroll
            for (int r = 0; r < 8; r++)
#pragma unroll
                for (int c = 0; c < 8; c++) acc[r][c] = fmaf(av[r], wv[c], acc[r][c]);
        }
        __syncthreads();
    }

    const int j0 = jb + jg * 8;     // 8-col group never straddles 192
    float* outp;
    int col0;
    if (j0 < 192) { outp = u_raw; col0 = j0; }
    else          { outp = res;   col0 = j0 - 192; }
#pragma unroll
    for (int r = 0; r < 8; r++) {
        const int row = l0 + lg * 8 + r;
        float* rowp = &outp[((size_t)b * 4096 + row) * 192 + col0];
        *reinterpret_cast<float4*>(rowp) =
            make_float4(acc[r][0], acc[r][1], acc[r][2], acc[r][3]);
        *reinterpret_cast<float4*>(rowp + 4) =
            make_float4(acc[r][4], acc[r][5], acc[r][6], acc[r][7]);
    }
}

// ---------------------------------------------------------------------------
// Kernel 2 (fused): depthwise causal conv1d(4)+bias+silu (LDS only)
//                   + x_proj GEMM  dbc[j] = sum_k u[b,l,k] * w[j,k]  (j<38)
// BM=64 rows, K=192 in 6 chunks of 32 channels. u is NOT written to global —
// the scan kernels recompute it from u_raw with a rolling conv window.
// j 0..5 -> dtarr (packed, 8-stride), j 6..21 -> Barr, j 22..37 -> Carr.
// ---------------------------------------------------------------------------
__global__ __launch_bounds__(256) void k_xproj(const float* __restrict__ u_raw,
                                               const float* __restrict__ w,
                                               const float* __restrict__ cw,
                                               const float* __restrict__ cb,
                                               float* __restrict__ dtarr,
                                               float* __restrict__ Barr,
                                               float* __restrict__ Carr)
{
    __shared__ float Ur[67][33];    // u_raw rows l0-3 .. l0+63 (halo)
    __shared__ float Us[64][36];    // conv output (=u tile)
    __shared__ float Ws[64 * 32];   // XOR-swizzled weights
    const int tid = threadIdx.x, tx = tid & 15, ty = tid >> 4;
    const int b = blockIdx.y;
    const int l0 = blockIdx.x * 64;

    float acc[4][4];
#pragma unroll
    for (int r = 0; r < 4; r++)
#pragma unroll
        for (int c = 0; c < 4; c++) acc[r][c] = 0.f;

    const int ch = tid & 31;        // conv channel within chunk
    const int lblk = tid >> 5;      // 0..7: 8 l-rows each

    for (int kb = 0; kb < 6; kb++) {
        // ---- stage Ur: 67 rows x 32 chans (8 f4-cols per row), 536 f4 total
        for (int idx = tid; idx < 536; idx += 256) {
            const int row = idx >> 3;
            const int c4 = idx & 7;
            const int gl = l0 - 3 + row;
            float4 v = make_float4(0.f, 0.f, 0.f, 0.f);
            if (gl >= 0)
                v = *reinterpret_cast<const float4*>(
                    &u_raw[((size_t)b * 4096 + gl) * 192 + kb * 32 + c4 * 4]);
            Ur[row][c4 * 4 + 0] = v.x;
            Ur[row][c4 * 4 + 1] = v.y;
            Ur[row][c4 * 4 + 2] = v.z;
            Ur[row][c4 * 4 + 3] = v.w;
        }
        // ---- stage Ws (swizzled), j<38 guard
        {
            const int k4 = tid & 7;
            const int jb0 = tid >> 3;
#pragma unroll
            for (int i = 0; i < 2; i++) {
                const int jl = jb0 + 32 * i;
                float4 v = make_float4(0.f, 0.f, 0.f, 0.f);
                if (jl < NDBC)
                    v = *reinterpret_cast<const float4*>(&w[(size_t)jl * 192 + kb * 32 + k4 * 4]);
                *reinterpret_cast<float4*>(
                    &Ws[jl * 32 + ((k4 ^ ((jl >> 2) & 7)) << 2)]) = v;
            }
        }
        __syncthreads();

        // ---- conv + silu: each thread does 8 rows of one channel
        {
            const float4 wc = *reinterpret_cast<const float4*>(&cw[(kb * 32 + ch) * 4]);
            const float bias = cb[kb * 32 + ch];
#pragma unroll
            for (int r = 0; r < 8; r++) {
                const int l = lblk * 8 + r;
                float s = bias;
                s = fmaf(wc.x, Ur[l + 0][ch], s);
                s = fmaf(wc.y, Ur[l + 1][ch], s);
                s = fmaf(wc.z, Ur[l + 2][ch], s);
                s = fmaf(wc.w, Ur[l + 3][ch], s);
                Us[l][ch] = siluf(s);
            }
        }
        __syncthreads();

        // ---- GEMM inner loop: A from Us, W from Ws
        const int sw = tx & 7;
#pragma unroll
        for (int k4 = 0; k4 < 8; k4++) {
            float4 a4[4];
#pragma unroll
            for (int r = 0; r < 4; r++)
                a4[r] = *reinterpret_cast<const float4*>(&Us[ty * 4 + r][k4 * 4]);
            float4 w4[4];
#pragma unroll
            for (int c = 0; c < 4; c++)
                w4[c] = *reinterpret_cast<const float4*>(
                    &Ws[(tx * 4 + c) * 32 + ((k4 ^ sw) << 2)]);
#pragma unroll
            for (int r = 0; r < 4; r++)
#pragma unroll
                for (int c = 0; c < 4; c++) {
                    acc[r][c] = fmaf(a4[r].x, w4[c].x, acc[r][c]);
                    acc[r][c] = fmaf(a4[r].y, w4[c].y, acc[r][c]);
                    acc[r][c] = fmaf(a4[r].z, w4[c].z, acc[r][c]);
                    acc[r][c] = fmaf(a4[r].w, w4[c].w, acc[r][c]);
                }
        }
        __syncthreads();
    }

#pragma unroll
    for (int r = 0; r < 4; r++) {
        const size_t row = (size_t)b * 4096 + l0 + ty * 4 + r;
#pragma unroll
        for (int c = 0; c < 4; c++) {
            const int j = tx * 4 + c;
            if (j < 6)       dtarr[row * 8 + j] = acc[r][c];
            else if (j < 22) Barr[row * 16 + (j - 6)] = acc[r][c];
            else if (j < 38) Carr[row * 16 + (j - 22)] = acc[r][c];
        }
    }
}

// ---------------------------------------------------------------------------
// Scan phase 1: one thread per (b, d, chunk); all 16 n in registers.
// Recomputes conv+silu (rolling 4-tap window on u_raw) and softplus-delta
// (from packed dtarr + per-thread dt_proj row) on the fly.
// ---------------------------------------------------------------------------
__global__ __launch_bounds__(192) void k_scan1(const float* __restrict__ u_raw,
                                               const float* __restrict__ dtarr,
                                               const float* __restrict__ Barr,
                                               const float* __restrict__ A_log,
                                               const float* __restrict__ dt_w,
                                               const float* __restrict__ dt_b,
                                               const float* __restrict__ cw,
                                               const float* __restrict__ cb,
                                               float* __restrict__ P,
                                               float* __restrict__ S)
{
    const int d = threadIdx.x;                 // 0..191
    const int c = blockIdx.x;                  // chunk
    const int b = blockIdx.y;

    float a[16];
    {
        const float4* al = reinterpret_cast<const float4*>(&A_log[d * 16]);
#pragma unroll
        for (int i = 0; i < 4; i++) {
            const float4 v = al[i];
            a[4 * i + 0] = -expf(v.x);
            a[4 * i + 1] = -expf(v.y);
            a[4 * i + 2] = -expf(v.z);
            a[4 * i + 3] = -expf(v.w);
        }
    }
    float dw[6];
#pragma unroll
    for (int k = 0; k < 6; k++) dw[k] = dt_w[d * 6 + k];
    const float db = dt_b[d];
    const float4 wc = *reinterpret_cast<const float4*>(&cw[d * 4]);
    const float cbias = cb[d];

    float st[16], p[16];
#pragma unroll
    for (int n = 0; n < 16; n++) { st[n] = 0.f; p[n] = 1.f; }

    const int t0 = c * CSTEP;
    const size_t g0 = (size_t)b * 4096 + t0;
    const float* up = u_raw + g0 * 192 + d;
    const float* dtp = dtarr + g0 * 8;
    const float* bp = Barr + g0 * 16;

    float w0 = 0.f, w1 = 0.f, w2 = 0.f;
    if (t0 >= 3) {
        w0 = up[-3 * 192];
        w1 = up[-2 * 192];
        w2 = up[-1 * 192];
    }

#pragma unroll 2
    for (int t = 0; t < CSTEP; t++) {
        const float w3 = up[t * 192];
        float uc = cbias;
        uc = fmaf(wc.x, w0, uc);
        uc = fmaf(wc.y, w1, uc);
        uc = fmaf(wc.z, w2, uc);
        uc = fmaf(wc.w, w3, uc);
        w0 = w1; w1 = w2; w2 = w3;
        const float ut = silu_fast(uc);

        const float4 q0 = *reinterpret_cast<const float4*>(dtp + t * 8);
        const float4 q1 = *reinterpret_cast<const float4*>(dtp + t * 8 + 4);
        float s = db;
        s = fmaf(q0.x, dw[0], s); s = fmaf(q0.y, dw[1], s);
        s = fmaf(q0.z, dw[2], s); s = fmaf(q0.w, dw[3], s);
        s = fmaf(q1.x, dw[4], s); s = fmaf(q1.y, dw[5], s);
        const float dt = softplus_fast(s);
        const float dtu = dt * ut;

        float Bv[16];
        {
            const float4* b4 = reinterpret_cast<const float4*>(bp + t * 16);
#pragma unroll
            for (int i = 0; i < 4; i++) {
                const float4 v = b4[i];
                Bv[4 * i + 0] = v.x; Bv[4 * i + 1] = v.y;
                Bv[4 * i + 2] = v.z; Bv[4 * i + 3] = v.w;
            }
        }
#pragma unroll
        for (int n = 0; n < 16; n++) {
            const float dA = __expf(dt * a[n]);
            p[n] *= dA;
            st[n] = fmaf(dA, st[n], dtu * Bv[n]);
        }
    }

    const size_t idx = (((size_t)b * NCHUNK + c) * 192 + d) * 16;
    float4* Pp = reinterpret_cast<float4*>(&P[idx]);
    float4* Sp = reinterpret_cast<float4*>(&S[idx]);
#pragma unroll
    for (int i = 0; i < 4; i++) {
        Pp[i] = make_float4(p[4 * i], p[4 * i + 1], p[4 * i + 2], p[4 * i + 3]);
        Sp[i] = make_float4(st[4 * i], st[4 * i + 1], st[4 * i + 2], st[4 * i + 3]);
    }
}

// ---------------------------------------------------------------------------
// Scan phase 2: sequential combine over chunks; S[c] overwritten with the
// init state for chunk c (carry BEFORE chunk c).
// ---------------------------------------------------------------------------
__global__ __launch_bounds__(256) void k_scan2(const float* __restrict__ P,
                                               float* __restrict__ S)
{
    const int dn = blockIdx.x * 256 + threadIdx.x;   // 0..3071
    const int b = blockIdx.y;
    float carry = 0.f;
    const size_t base = (size_t)b * NCHUNK * 3072 + dn;
#pragma unroll 8
    for (int c = 0; c < NCHUNK; c++) {
        const size_t idx = base + (size_t)c * 3072;
        const float p = P[idx];
        const float s = S[idx];
        S[idx] = carry;
        carry = fmaf(p, carry, s);
    }
}

// ---------------------------------------------------------------------------
// Scan phase 3: re-run recurrence from correct init; y reduced in-register
// over n; fused epilogue y = (y + u*D) * silu(res). conv/delta recomputed.
// ---------------------------------------------------------------------------
__global__ __launch_bounds__(192) void k_scan3(const float* __restrict__ u_raw,
                                               const float* __restrict__ dtarr,
                                               const float* __restrict__ Barr,
                                               const float* __restrict__ Carr,
                                               const float* __restrict__ A_log,
                                               const float* __restrict__ dt_w,
                                               const float* __restrict__ dt_b,
                                               const float* __restrict__ cw,
                                               const float* __restrict__ cb,
                                               const float* __restrict__ S,
                                               const float* __restrict__ Dp,
                                               const float* __restrict__ res,
                                               float* __restrict__ y)
{
    const int d = threadIdx.x;
    const int c = blockIdx.x;
    const int b = blockIdx.y;

    float a[16];
    {
        const float4* al = reinterpret_cast<const float4*>(&A_log[d * 16]);
#pragma unroll
        for (int i = 0; i < 4; i++) {
            const float4 v = al[i];
            a[4 * i + 0] = -expf(v.x);
            a[4 * i + 1] = -expf(v.y);
            a[4 * i + 2] = -expf(v.z);
            a[4 * i + 3] = -expf(v.w);
        }
    }
    float dw[6];
#pragma unroll
    for (int k = 0; k < 6; k++) dw[k] = dt_w[d * 6 + k];
    const float db = dt_b[d];
    const float4 wc = *reinterpret_cast<const float4*>(&cw[d * 4]);
    const float cbias = cb[d];
    const float Dd = Dp[d];

    float st[16];
    {
        const float4* Sp = reinterpret_cast<const float4*>(
            &S[(((size_t)b * NCHUNK + c) * 192 + d) * 16]);
#pragma unroll
        for (int i = 0; i < 4; i++) {
            const float4 v = Sp[i];
            st[4 * i + 0] = v.x; st[4 * i + 1] = v.y;
            st[4 * i + 2] = v.z; st[4 * i + 3] = v.w;
        }
    }

    const int t0 = c * CSTEP;
    const size_t g0 = (size_t)b * 4096 + t0;
    const float* up = u_raw + g0 * 192 + d;
    const float* rp = res + g0 * 192 + d;
    float* yp = y + g0 * 192 + d;
    const float* dtp = dtarr + g0 * 8;
    const float* bp = Barr + g0 * 16;
    const float* cp = Carr + g0 * 16;

    float w0 = 0.f, w1 = 0.f, w2 = 0.f;
    if (t0 >= 3) {
        w0 = up[-3 * 192];
        w1 = up[-2 * 192];
        w2 = up[-1 * 192];
    }

#pragma unroll 2
    for (int t = 0; t < CSTEP; t++) {
        const float w3 = up[t * 192];
        float uc = cbias;
        uc = fmaf(wc.x, w0, uc);
        uc = fmaf(wc.y, w1, uc);
        uc = fmaf(wc.z, w2, uc);
        uc = fmaf(wc.w, w3, uc);
        w0 = w1; w1 = w2; w2 = w3;
        const float ut = silu_fast(uc);

        const float4 q0 = *reinterpret_cast<const float4*>(dtp + t * 8);
        const float4 q1 = *reinterpret_cast<const float4*>(dtp + t * 8 + 4);
        float s = db;
        s = fmaf(q0.x, dw[0], s); s = fmaf(q0.y, dw[1], s);
        s = fmaf(q0.z, dw[2], s); s = fmaf(q0.w, dw[3], s);
        s = fmaf(q1.x, dw[4], s); s = fmaf(q1.y, dw[5], s);
        const float dt = softplus_fast(s);
        const float dtu = dt * ut;

        float Bv[16], Cv[16];
        {
            const float4* b4 = reinterpret_cast<const float4*>(bp + t * 16);
            const float4* c4 = reinterpret_cast<const float4*>(cp + t * 16);
#pragma unroll
            for (int i = 0; i < 4; i++) {
                const float4 v = b4[i];
                Bv[4 * i + 0] = v.x; Bv[4 * i + 1] = v.y;
                Bv[4 * i + 2] = v.z; Bv[4 * i + 3] = v.w;
                const float4 w = c4[i];
                Cv[4 * i + 0] = w.x; Cv[4 * i + 1] = w.y;
                Cv[4 * i + 2] = w.z; Cv[4 * i + 3] = w.w;
            }
        }
        float yt = 0.f;
#pragma unroll
        for (int n = 0; n < 16; n++) {
            const float dA = __expf(dt * a[n]);
            st[n] = fmaf(dA, st[n], dtu * Bv[n]);
            yt = fmaf(st[n], Cv[n], yt);
        }
        const float r = rp[t * 192];
        yp[t * 192] = fmaf(ut, Dd, yt) * silu_fast(r);
    }
}

// ---------------------------------------------------------------------------
// Kernel 8: out_proj GEMM with output transpose + channel flip.
// d_out[b, 95-j, l] = sum_k y[b,l,k] * w[j,k].  Swizzled W tile.
// ---------------------------------------------------------------------------
__global__ __launch_bounds__(256) void k_outproj(const float* __restrict__ y,
                                                 const float* __restrict__ w,
                                                 float* __restrict__ out)
{
    __shared__ float Ws[64 * 32];
    const int tid = threadIdx.x, tx = tid & 15, ty = tid >> 4;
    const int b = blockIdx.z;
    const int l0 = blockIdx.x * 128;
    const int jb = blockIdx.y * 64;

    float acc[8][4];
#pragma unroll
    for (int r = 0; r < 8; r++)
#pragma unroll
        for (int c = 0; c < 4; c++) acc[r][c] = 0.f;

    for (int kb = 0; kb < 6; kb++) {
        {
            const int k4 = tid & 7;
            const int jb0 = tid >> 3;
#pragma unroll
            for (int i = 0; i < 2; i++) {
                const int jl = jb0 + 32 * i;
                const int j = jb + jl;
                float4 v = make_float4(0.f, 0.f, 0.f, 0.f);
                if (j < 96)
                    v = *reinterpret_cast<const float4*>(&w[(size_t)j * 192 + kb * 32 + k4 * 4]);
                *reinterpret_cast<float4*>(
                    &Ws[jl * 32 + ((k4 ^ ((jl >> 2) & 7)) << 2)]) = v;
            }
        }
        __syncthreads();
        const int sw = tx & 7;
#pragma unroll
        for (int k4 = 0; k4 < 8; k4++) {
            float4 a4[8];
#pragma unroll
            for (int r = 0; r < 8; r++) {
                const int row = l0 + ty * 8 + r;
                a4[r] = *reinterpret_cast<const float4*>(
                    &y[((size_t)b * 4096 + row) * 192 + kb * 32 + k4 * 4]);
            }
            float4 w4[4];
#pragma unroll
            for (int c = 0; c < 4; c++)
                w4[c] = *reinterpret_cast<const float4*>(
                    &Ws[(tx * 4 + c) * 32 + ((k4 ^ sw) << 2)]);
#pragma unroll
            for (int r = 0; r < 8; r++)
#pragma unroll
                for (int c = 0; c < 4; c++) {
                    acc[r][c] = fmaf(a4[r].x, w4[c].x, acc[r][c]);
                    acc[r][c] = fmaf(a4[r].y, w4[c].y, acc[r][c]);
                    acc[r][c] = fmaf(a4[r].z, w4[c].z, acc[r][c]);
                    acc[r][c] = fmaf(a4[r].w, w4[c].w, acc[r][c]);
                }
        }
        __syncthreads();
    }
#pragma unroll
    for (int c = 0; c < 4; c++) {
        const int j = jb + tx * 4 + c;
        if (j < 96) {
            const int ch = 95 - j;
            const float4 v0 = make_float4(acc[0][c], acc[1][c], acc[2][c], acc[3][c]);
            const float4 v1 = make_float4(acc[4][c], acc[5][c], acc[6][c], acc[7][c]);
            const size_t base = ((size_t)b * 96 + ch) * 4096 + l0 + ty * 8;
            *reinterpret_cast<float4*>(&out[base]) = v0;
            *reinterpret_cast<float4*>(&out[base + 4]) = v1;
        }
    }
}

extern "C" void kernel_launch(void* const* d_in, const int* in_sizes, int n_in,
                              void* d_out, int out_size, void* d_ws, size_t ws_size,
                              hipStream_t stream)
{
    const float* x       = (const float*)d_in[0];
    const float* in_w    = (const float*)d_in[1];
    const float* conv_w  = (const float*)d_in[2];
    const float* conv_b  = (const float*)d_in[3];
    const float* xproj_w = (const float*)d_in[4];
    const float* dt_w    = (const float*)d_in[5];
    const float* dt_b    = (const float*)d_in[6];
    const float* A_log   = (const float*)d_in[7];
    const float* Dp      = (const float*)d_in[8];
    const float* out_w   = (const float*)d_in[9];

    // workspace layout (floats). total ~26.5M floats = 101 MB
    float* ws    = (float*)d_ws;
    float* u_raw = ws;                        // 6291456
    float* res   = u_raw + 6291456;           // 6291456
    float* yfin  = res   + 6291456;           // 6291456 (scan3 out; u_raw stays live)
    float* dtarr = yfin  + 6291456;           // 262144
    float* Barr  = dtarr + 262144;            // 524288
    float* Carr  = Barr  + 524288;            // 524288
    float* P     = Carr  + 524288;            // 3145728
    float* S     = P     + 3145728;           // 3145728

    hipLaunchKernelGGL(k_in_proj, dim3(32, 3, 8), dim3(256), 0, stream, x, in_w, u_raw, res);
    hipLaunchKernelGGL(k_xproj,   dim3(64, 8),    dim3(256), 0, stream,
                       u_raw, xproj_w, conv_w, conv_b, dtarr, Barr, Carr);
    hipLaunchKernelGGL(k_scan1,   dim3(NCHUNK, 8), dim3(192), 0, stream,
                       u_raw, dtarr, Barr, A_log, dt_w, dt_b, conv_w, conv_b, P, S);
    hipLaunchKernelGGL(k_scan2,   dim3(12, 8),    dim3(256), 0, stream, P, S);
    hipLaunchKernelGGL(k_scan3,   dim3(NCHUNK, 8), dim3(192), 0, stream,
                       u_raw, dtarr, Barr, Carr, A_log, dt_w, dt_b, conv_w, conv_b,
                       S, Dp, res, yfin);
    hipLaunchKernelGGL(k_outproj, dim3(32, 2, 8), dim3(256), 0, stream, yfin, out_w, (float*)d_out);
}

// Round 6
// 273.236 us; speedup vs baseline: 1.6809x; 1.0029x over previous
//
#include <hip/hip_runtime.h>
#include <math.h>

// Problem constants (DRMamba): b=8, c=d_model=96, l=64*64=4096, d_inner=192,
// d_state=16, d_conv=4, dt_rank=6, REVERSE=True (channel flip folded into
// weight indexing on both ends).
#define NBATCH 8
#define SEQL   4096
#define DMODEL 96
#define DINNER 192
#define DSTATE 16
#define NDBC   38      // dt_rank + 2*d_state
#define NCHUNK 128
#define CSTEP  32      // NCHUNK*CSTEP == SEQL

__device__ __forceinline__ float siluf(float x) {
    return x / (1.f + expf(-x));
}
__device__ __forceinline__ float silu_fast(float x) {
    return x * __builtin_amdgcn_rcpf(1.f + __expf(-x));
}
__device__ __forceinline__ float softplus_fast(float x) {
    return (x > 15.f) ? x : __logf(1.f + __expf(x));
}

// ---------------------------------------------------------------------------
// Kernel 1: in_proj GEMM.  out[b,l,j] = sum_m x[b,95-m,l] * w[j,m]
// j<192 -> u_raw, j>=192 -> res.
// 512 threads = 8 waves. BM=256 (l), BN=64 (j); each WAVE owns 8 j-cols, its
// 64 lanes split the 256 l-rows (4 each). Key property: the W fragment read
// is wave-uniform -> LDS broadcast (conflict-free by construction); the A
// read is contiguous full-wave b128 (bandwidth-only). Per k-iter/wave:
// ~15 LDS-port cyc vs 64 FMA cyc -> VALU-bound.
// LDS 41 KB -> 3 blocks/CU; grid 768 = exactly 3/CU (no residency tail).
// ---------------------------------------------------------------------------
__global__ __launch_bounds__(512) void k_in_proj(const float* __restrict__ x,
                                                 const float* __restrict__ w,
                                                 float* __restrict__ u_raw,
                                                 float* __restrict__ res)
{
    __shared__ float As[32][256];   // 32 KB, [k][l]
    __shared__ float Wt[32][72];    // 9.2 KB, [k][j] (stride 72: 288B, 16B-mult)
    const int tid = threadIdx.x;
    const int lane = tid & 63;
    const int wv = tid >> 6;        // 0..7
    const int b = blockIdx.z;
    const int l0 = blockIdx.y * 256;
    const int jb = blockIdx.x * 64;
    const int j0 = jb + wv * 8;

    float acc[4][8];
#pragma unroll
    for (int r = 0; r < 4; r++)
#pragma unroll
        for (int c = 0; c < 8; c++) acc[r][c] = 0.f;

    for (int kb = 0; kb < 3; kb++) {
        // A tile: 32 m x 256 l. Per wave: row uniform, 64 lanes contiguous f4
        // -> perfectly coalesced global, bandwidth-pattern LDS store.
#pragma unroll
        for (int i = 0; i < 4; i++) {
            const int idx = tid + 512 * i;
            const int m = idx >> 6;       // 0..31
            const int c4 = idx & 63;      // f4 col
            const float4 v = *reinterpret_cast<const float4*>(
                &x[((size_t)b * 96 + (95 - (kb * 32 + m))) * 4096 + l0 + c4 * 4]);
            *reinterpret_cast<float4*>(&As[m][c4 * 4]) = v;
        }
        // W tile: 64 j x 32 k, transposed into Wt[k][j]. j = tid&63 makes
        // store banks (8i + j) % 32 -> 2-way (free). W is tiny/L2-resident.
        {
            const int j = tid & 63;
            const int k4 = tid >> 6;      // 0..7
            const float4 v = *reinterpret_cast<const float4*>(
                &w[(size_t)(jb + j) * 96 + kb * 32 + k4 * 4]);
            Wt[k4 * 4 + 0][j] = v.x;
            Wt[k4 * 4 + 1][j] = v.y;
            Wt[k4 * 4 + 2][j] = v.z;
            Wt[k4 * 4 + 3][j] = v.w;
        }
        __syncthreads();
#pragma unroll
        for (int k = 0; k < 32; k++) {
            const float4 a4 = *reinterpret_cast<const float4*>(&As[k][lane * 4]);
            const float4 wA = *reinterpret_cast<const float4*>(&Wt[k][wv * 8]);
            const float4 wB = *reinterpret_cast<const float4*>(&Wt[k][wv * 8 + 4]);
            const float av[4] = {a4.x, a4.y, a4.z, a4.w};
            const float wvv[8] = {wA.x, wA.y, wA.z, wA.w, wB.x, wB.y, wB.z, wB.w};
#pragma unroll
            for (int r = 0; r < 4; r++)
#pragma unroll
                for (int c = 0; c < 8; c++) acc[r][c] = fmaf(av[r], wvv[c], acc[r][c]);
        }
        __syncthreads();
    }

    // j-group of 8 never straddles 192 (jb is 64-aligned).
    float* outp;
    int col0;
    if (j0 < 192) { outp = u_raw; col0 = j0; }
    else          { outp = res;   col0 = j0 - 192; }
#pragma unroll
    for (int r = 0; r < 4; r++) {
        const int row = l0 + lane * 4 + r;
        float* rowp = &outp[((size_t)b * 4096 + row) * 192 + col0];
        *reinterpret_cast<float4*>(rowp) =
            make_float4(acc[r][0], acc[r][1], acc[r][2], acc[r][3]);
        *reinterpret_cast<float4*>(rowp + 4) =
            make_float4(acc[r][4], acc[r][5], acc[r][6], acc[r][7]);
    }
}

// ---------------------------------------------------------------------------
// Kernel 2 (fused): depthwise causal conv1d(4)+bias+silu (LDS only)
//                   + x_proj GEMM  dbc[j] = sum_k u[b,l,k] * w[j,k]  (j<38)
// BM=64 rows, K=192 in 6 chunks of 32 channels. u is NOT written to global —
// the scan kernels recompute it from u_raw with a rolling conv window.
// j 0..5 -> dtarr (packed, 8-stride), j 6..21 -> Barr, j 22..37 -> Carr.
// ---------------------------------------------------------------------------
__global__ __launch_bounds__(256) void k_xproj(const float* __restrict__ u_raw,
                                               const float* __restrict__ w,
                                               const float* __restrict__ cw,
                                               const float* __restrict__ cb,
                                               float* __restrict__ dtarr,
                                               float* __restrict__ Barr,
                                               float* __restrict__ Carr)
{
    __shared__ float Ur[67][33];    // u_raw rows l0-3 .. l0+63 (halo)
    __shared__ float Us[64][36];    // conv output (=u tile)
    __shared__ float Ws[64 * 32];   // XOR-swizzled weights
    const int tid = threadIdx.x, tx = tid & 15, ty = tid >> 4;
    const int b = blockIdx.y;
    const int l0 = blockIdx.x * 64;

    float acc[4][4];
#pragma unroll
    for (int r = 0; r < 4; r++)
#pragma unroll
        for (int c = 0; c < 4; c++) acc[r][c] = 0.f;

    const int ch = tid & 31;        // conv channel within chunk
    const int lblk = tid >> 5;      // 0..7: 8 l-rows each

    for (int kb = 0; kb < 6; kb++) {
        // ---- stage Ur: 67 rows x 32 chans (8 f4-cols per row), 536 f4 total
        for (int idx = tid; idx < 536; idx += 256) {
            const int row = idx >> 3;
            const int c4 = idx & 7;
            const int gl = l0 - 3 + row;
            float4 v = make_float4(0.f, 0.f, 0.f, 0.f);
            if (gl >= 0)
                v = *reinterpret_cast<const float4*>(
                    &u_raw[((size_t)b * 4096 + gl) * 192 + kb * 32 + c4 * 4]);
            Ur[row][c4 * 4 + 0] = v.x;
            Ur[row][c4 * 4 + 1] = v.y;
            Ur[row][c4 * 4 + 2] = v.z;
            Ur[row][c4 * 4 + 3] = v.w;
        }
        // ---- stage Ws (swizzled), j<38 guard
        {
            const int k4 = tid & 7;
            const int jb0 = tid >> 3;
#pragma unroll
            for (int i = 0; i < 2; i++) {
                const int jl = jb0 + 32 * i;
                float4 v = make_float4(0.f, 0.f, 0.f, 0.f);
                if (jl < NDBC)
                    v = *reinterpret_cast<const float4*>(&w[(size_t)jl * 192 + kb * 32 + k4 * 4]);
                *reinterpret_cast<float4*>(
                    &Ws[jl * 32 + ((k4 ^ ((jl >> 2) & 7)) << 2)]) = v;
            }
        }
        __syncthreads();

        // ---- conv + silu: each thread does 8 rows of one channel
        {
            const float4 wc = *reinterpret_cast<const float4*>(&cw[(kb * 32 + ch) * 4]);
            const float bias = cb[kb * 32 + ch];
#pragma unroll
            for (int r = 0; r < 8; r++) {
                const int l = lblk * 8 + r;
                float s = bias;
                s = fmaf(wc.x, Ur[l + 0][ch], s);
                s = fmaf(wc.y, Ur[l + 1][ch], s);
                s = fmaf(wc.z, Ur[l + 2][ch], s);
                s = fmaf(wc.w, Ur[l + 3][ch], s);
                Us[l][ch] = siluf(s);
            }
        }
        __syncthreads();

        // ---- GEMM inner loop: A from Us, W from Ws
        const int sw = tx & 7;
#pragma unroll
        for (int k4 = 0; k4 < 8; k4++) {
            float4 a4[4];
#pragma unroll
            for (int r = 0; r < 4; r++)
                a4[r] = *reinterpret_cast<const float4*>(&Us[ty * 4 + r][k4 * 4]);
            float4 w4[4];
#pragma unroll
            for (int c = 0; c < 4; c++)
                w4[c] = *reinterpret_cast<const float4*>(
                    &Ws[(tx * 4 + c) * 32 + ((k4 ^ sw) << 2)]);
#pragma unroll
            for (int r = 0; r < 4; r++)
#pragma unroll
                for (int c = 0; c < 4; c++) {
                    acc[r][c] = fmaf(a4[r].x, w4[c].x, acc[r][c]);
                    acc[r][c] = fmaf(a4[r].y, w4[c].y, acc[r][c]);
                    acc[r][c] = fmaf(a4[r].z, w4[c].z, acc[r][c]);
                    acc[r][c] = fmaf(a4[r].w, w4[c].w, acc[r][c]);
                }
        }
        __syncthreads();
    }

#pragma unroll
    for (int r = 0; r < 4; r++) {
        const size_t row = (size_t)b * 4096 + l0 + ty * 4 + r;
#pragma unroll
        for (int c = 0; c < 4; c++) {
            const int j = tx * 4 + c;
            if (j < 6)       dtarr[row * 8 + j] = acc[r][c];
            else if (j < 22) Barr[row * 16 + (j - 6)] = acc[r][c];
            else if (j < 38) Carr[row * 16 + (j - 22)] = acc[r][c];
        }
    }
}

// ---------------------------------------------------------------------------
// Scan phase 1: one thread per (b, d, chunk); all 16 n in registers.
// Recomputes conv+silu (rolling 4-tap window on u_raw) and softplus-delta
// (from packed dtarr + per-thread dt_proj row) on the fly.
// ---------------------------------------------------------------------------
__global__ __launch_bounds__(192) void k_scan1(const float* __restrict__ u_raw,
                                               const float* __restrict__ dtarr,
                                               const float* __restrict__ Barr,
                                               const float* __restrict__ A_log,
                                               const float* __restrict__ dt_w,
                                               const float* __restrict__ dt_b,
                                               const float* __restrict__ cw,
                                               const float* __restrict__ cb,
                                               float* __restrict__ P,
                                               float* __restrict__ S)
{
    const int d = threadIdx.x;                 // 0..191
    const int c = blockIdx.x;                  // chunk
    const int b = blockIdx.y;

    float a[16];
    {
        const float4* al = reinterpret_cast<const float4*>(&A_log[d * 16]);
#pragma unroll
        for (int i = 0; i < 4; i++) {
            const float4 v = al[i];
            a[4 * i + 0] = -expf(v.x);
            a[4 * i + 1] = -expf(v.y);
            a[4 * i + 2] = -expf(v.z);
            a[4 * i + 3] = -expf(v.w);
        }
    }
    float dw[6];
#pragma unroll
    for (int k = 0; k < 6; k++) dw[k] = dt_w[d * 6 + k];
    const float db = dt_b[d];
    const float4 wc = *reinterpret_cast<const float4*>(&cw[d * 4]);
    const float cbias = cb[d];

    float st[16], p[16];
#pragma unroll
    for (int n = 0; n < 16; n++) { st[n] = 0.f; p[n] = 1.f; }

    const int t0 = c * CSTEP;
    const size_t g0 = (size_t)b * 4096 + t0;
    const float* up = u_raw + g0 * 192 + d;
    const float* dtp = dtarr + g0 * 8;
    const float* bp = Barr + g0 * 16;

    float w0 = 0.f, w1 = 0.f, w2 = 0.f;
    if (t0 >= 3) {
        w0 = up[-3 * 192];
        w1 = up[-2 * 192];
        w2 = up[-1 * 192];
    }

#pragma unroll 2
    for (int t = 0; t < CSTEP; t++) {
        const float w3 = up[t * 192];
        float uc = cbias;
        uc = fmaf(wc.x, w0, uc);
        uc = fmaf(wc.y, w1, uc);
        uc = fmaf(wc.z, w2, uc);
        uc = fmaf(wc.w, w3, uc);
        w0 = w1; w1 = w2; w2 = w3;
        const float ut = silu_fast(uc);

        const float4 q0 = *reinterpret_cast<const float4*>(dtp + t * 8);
        const float4 q1 = *reinterpret_cast<const float4*>(dtp + t * 8 + 4);
        float s = db;
        s = fmaf(q0.x, dw[0], s); s = fmaf(q0.y, dw[1], s);
        s = fmaf(q0.z, dw[2], s); s = fmaf(q0.w, dw[3], s);
        s = fmaf(q1.x, dw[4], s); s = fmaf(q1.y, dw[5], s);
        const float dt = softplus_fast(s);
        const float dtu = dt * ut;

        float Bv[16];
        {
            const float4* b4 = reinterpret_cast<const float4*>(bp + t * 16);
#pragma unroll
            for (int i = 0; i < 4; i++) {
                const float4 v = b4[i];
                Bv[4 * i + 0] = v.x; Bv[4 * i + 1] = v.y;
                Bv[4 * i + 2] = v.z; Bv[4 * i + 3] = v.w;
            }
        }
#pragma unroll
        for (int n = 0; n < 16; n++) {
            const float dA = __expf(dt * a[n]);
            p[n] *= dA;
            st[n] = fmaf(dA, st[n], dtu * Bv[n]);
        }
    }

    const size_t idx = (((size_t)b * NCHUNK + c) * 192 + d) * 16;
    float4* Pp = reinterpret_cast<float4*>(&P[idx]);
    float4* Sp = reinterpret_cast<float4*>(&S[idx]);
#pragma unroll
    for (int i = 0; i < 4; i++) {
        Pp[i] = make_float4(p[4 * i], p[4 * i + 1], p[4 * i + 2], p[4 * i + 3]);
        Sp[i] = make_float4(st[4 * i], st[4 * i + 1], st[4 * i + 2], st[4 * i + 3]);
    }
}

// ---------------------------------------------------------------------------
// Scan phase 2: sequential combine over chunks; S[c] overwritten with the
// init state for chunk c (carry BEFORE chunk c).
// ---------------------------------------------------------------------------
__global__ __launch_bounds__(256) void k_scan2(const float* __restrict__ P,
                                               float* __restrict__ S)
{
    const int dn = blockIdx.x * 256 + threadIdx.x;   // 0..3071
    const int b = blockIdx.y;
    float carry = 0.f;
    const size_t base = (size_t)b * NCHUNK * 3072 + dn;
#pragma unroll 8
    for (int c = 0; c < NCHUNK; c++) {
        const size_t idx = base + (size_t)c * 3072;
        const float p = P[idx];
        const float s = S[idx];
        S[idx] = carry;
        carry = fmaf(p, carry, s);
    }
}

// ---------------------------------------------------------------------------
// Scan phase 3: re-run recurrence from correct init; y reduced in-register
// over n; fused epilogue y = (y + u*D) * silu(res). conv/delta recomputed.
// ---------------------------------------------------------------------------
__global__ __launch_bounds__(192) void k_scan3(const float* __restrict__ u_raw,
                                               const float* __restrict__ dtarr,
                                               const float* __restrict__ Barr,
                                               const float* __restrict__ Carr,
                                               const float* __restrict__ A_log,
                                               const float* __restrict__ dt_w,
                                               const float* __restrict__ dt_b,
                                               const float* __restrict__ cw,
                                               const float* __restrict__ cb,
                                               const float* __restrict__ S,
                                               const float* __restrict__ Dp,
                                               const float* __restrict__ res,
                                               float* __restrict__ y)
{
    const int d = threadIdx.x;
    const int c = blockIdx.x;
    const int b = blockIdx.y;

    float a[16];
    {
        const float4* al = reinterpret_cast<const float4*>(&A_log[d * 16]);
#pragma unroll
        for (int i = 0; i < 4; i++) {
            const float4 v = al[i];
            a[4 * i + 0] = -expf(v.x);
            a[4 * i + 1] = -expf(v.y);
            a[4 * i + 2] = -expf(v.z);
            a[4 * i + 3] = -expf(v.w);
        }
    }
    float dw[6];
#pragma unroll
    for (int k = 0; k < 6; k++) dw[k] = dt_w[d * 6 + k];
    const float db = dt_b[d];
    const float4 wc = *reinterpret_cast<const float4*>(&cw[d * 4]);
    const float cbias = cb[d];
    const float Dd = Dp[d];

    float st[16];
    {
        const float4* Sp = reinterpret_cast<const float4*>(
            &S[(((size_t)b * NCHUNK + c) * 192 + d) * 16]);
#pragma unroll
        for (int i = 0; i < 4; i++) {
            const float4 v = Sp[i];
            st[4 * i + 0] = v.x; st[4 * i + 1] = v.y;
            st[4 * i + 2] = v.z; st[4 * i + 3] = v.w;
        }
    }

    const int t0 = c * CSTEP;
    const size_t g0 = (size_t)b * 4096 + t0;
    const float* up = u_raw + g0 * 192 + d;
    const float* rp = res + g0 * 192 + d;
    float* yp = y + g0 * 192 + d;
    const float* dtp = dtarr + g0 * 8;
    const float* bp = Barr + g0 * 16;
    const float* cp = Carr + g0 * 16;

    float w0 = 0.f, w1 = 0.f, w2 = 0.f;
    if (t0 >= 3) {
        w0 = up[-3 * 192];
        w1 = up[-2 * 192];
        w2 = up[-1 * 192];
    }

#pragma unroll 2
    for (int t = 0; t < CSTEP; t++) {
        const float w3 = up[t * 192];
        float uc = cbias;
        uc = fmaf(wc.x, w0, uc);
        uc = fmaf(wc.y, w1, uc);
        uc = fmaf(wc.z, w2, uc);
        uc = fmaf(wc.w, w3, uc);
        w0 = w1; w1 = w2; w2 = w3;
        const float ut = silu_fast(uc);

        const float4 q0 = *reinterpret_cast<const float4*>(dtp + t * 8);
        const float4 q1 = *reinterpret_cast<const float4*>(dtp + t * 8 + 4);
        float s = db;
        s = fmaf(q0.x, dw[0], s); s = fmaf(q0.y, dw[1], s);
        s = fmaf(q0.z, dw[2], s); s = fmaf(q0.w, dw[3], s);
        s = fmaf(q1.x, dw[4], s); s = fmaf(q1.y, dw[5], s);
        const float dt = softplus_fast(s);
        const float dtu = dt * ut;

        float Bv[16], Cv[16];
        {
            const float4* b4 = reinterpret_cast<const float4*>(bp + t * 16);
            const float4* c4 = reinterpret_cast<const float4*>(cp + t * 16);
#pragma unroll
            for (int i = 0; i < 4; i++) {
                const float4 v = b4[i];
                Bv[4 * i + 0] = v.x; Bv[4 * i + 1] = v.y;
                Bv[4 * i + 2] = v.z; Bv[4 * i + 3] = v.w;
                const float4 w = c4[i];
                Cv[4 * i + 0] = w.x; Cv[4 * i + 1] = w.y;
                Cv[4 * i + 2] = w.z; Cv[4 * i + 3] = w.w;
            }
        }
        float yt = 0.f;
#pragma unroll
        for (int n = 0; n < 16; n++) {
            const float dA = __expf(dt * a[n]);
            st[n] = fmaf(dA, st[n], dtu * Bv[n]);
            yt = fmaf(st[n], Cv[n], yt);
        }
        const float r = rp[t * 192];
        yp[t * 192] = fmaf(ut, Dd, yt) * silu_fast(r);
    }
}

// ---------------------------------------------------------------------------
// Kernel 8: out_proj GEMM with output transpose + channel flip.
// d_out[b, 95-j, l] = sum_k y[b,l,k] * w[j,k].  Swizzled W tile.
// ---------------------------------------------------------------------------
__global__ __launch_bounds__(256) void k_outproj(const float* __restrict__ y,
                                                 const float* __restrict__ w,
                                                 float* __restrict__ out)
{
    __shared__ float Ws[64 * 32];
    const int tid = threadIdx.x, tx = tid & 15, ty = tid >> 4;
    const int b = blockIdx.z;
    const int l0 = blockIdx.x * 128;
    const int jb = blockIdx.y * 64;

    float acc[8][4];
#pragma unroll
    for (int r = 0; r < 8; r++)
#pragma unroll
        for (int c = 0; c < 4; c++) acc[r][c] = 0.f;

    for (int kb = 0; kb < 6; kb++) {
        {
            const int k4 = tid & 7;
            const int jb0 = tid >> 3;
#pragma unroll
            for (int i = 0; i < 2; i++) {
                const int jl = jb0 + 32 * i;
                const int j = jb + jl;
                float4 v = make_float4(0.f, 0.f, 0.f, 0.f);
                if (j < 96)
                    v = *reinterpret_cast<const float4*>(&w[(size_t)j * 192 + kb * 32 + k4 * 4]);
                *reinterpret_cast<float4*>(
                    &Ws[jl * 32 + ((k4 ^ ((jl >> 2) & 7)) << 2)]) = v;
            }
        }
        __syncthreads();
        const int sw = tx & 7;
#pragma unroll
        for (int k4 = 0; k4 < 8; k4++) {
            float4 a4[8];
#pragma unroll
            for (int r = 0; r < 8; r++) {
                const int row = l0 + ty * 8 + r;
                a4[r] = *reinterpret_cast<const float4*>(
                    &y[((size_t)b * 4096 + row) * 192 + kb * 32 + k4 * 4]);
            }
            float4 w4[4];
#pragma unroll
            for (int c = 0; c < 4; c++)
                w4[c] = *reinterpret_cast<const float4*>(
                    &Ws[(tx * 4 + c) * 32 + ((k4 ^ sw) << 2)]);
#pragma unroll
            for (int r = 0; r < 8; r++)
#pragma unroll
                for (int c = 0; c < 4; c++) {
                    acc[r][c] = fmaf(a4[r].x, w4[c].x, acc[r][c]);
                    acc[r][c] = fmaf(a4[r].y, w4[c].y, acc[r][c]);
                    acc[r][c] = fmaf(a4[r].z, w4[c].z, acc[r][c]);
                    acc[r][c] = fmaf(a4[r].w, w4[c].w, acc[r][c]);
                }
        }
        __syncthreads();
    }
#pragma unroll
    for (int c = 0; c < 4; c++) {
        const int j = jb + tx * 4 + c;
        if (j < 96) {
            const int ch = 95 - j;
            const float4 v0 = make_float4(acc[0][c], acc[1][c], acc[2][c], acc[3][c]);
            const float4 v1 = make_float4(acc[4][c], acc[5][c], acc[6][c], acc[7][c]);
            const size_t base = ((size_t)b * 96 + ch) * 4096 + l0 + ty * 8;
            *reinterpret_cast<float4*>(&out[base]) = v0;
            *reinterpret_cast<float4*>(&out[base + 4]) = v1;
        }
    }
}

extern "C" void kernel_launch(void* const* d_in, const int* in_sizes, int n_in,
                              void* d_out, int out_size, void* d_ws, size_t ws_size,
                              hipStream_t stream)
{
    const float* x       = (const float*)d_in[0];
    const float* in_w    = (const float*)d_in[1];
    const float* conv_w  = (const float*)d_in[2];
    const float* conv_b  = (const float*)d_in[3];
    const float* xproj_w = (const float*)d_in[4];
    const float* dt_w    = (const float*)d_in[5];
    const float* dt_b    = (const float*)d_in[6];
    const float* A_log   = (const float*)d_in[7];
    const float* Dp      = (const float*)d_in[8];
    const float* out_w   = (const float*)d_in[9];

    // workspace layout (floats). total ~26.5M floats = 101 MB
    float* ws    = (float*)d_ws;
    float* u_raw = ws;                        // 6291456
    float* res   = u_raw + 6291456;           // 6291456
    float* yfin  = res   + 6291456;           // 6291456 (scan3 out; u_raw stays live)
    float* dtarr = yfin  + 6291456;           // 262144
    float* Barr  = dtarr + 262144;            // 524288
    float* Carr  = Barr  + 524288;            // 524288
    float* P     = Carr  + 524288;            // 3145728
    float* S     = P     + 3145728;           // 3145728

    hipLaunchKernelGGL(k_in_proj, dim3(6, 16, 8), dim3(512), 0, stream, x, in_w, u_raw, res);
    hipLaunchKernelGGL(k_xproj,   dim3(64, 8),    dim3(256), 0, stream,
                       u_raw, xproj_w, conv_w, conv_b, dtarr, Barr, Carr);
    hipLaunchKernelGGL(k_scan1,   dim3(NCHUNK, 8), dim3(192), 0, stream,
                       u_raw, dtarr, Barr, A_log, dt_w, dt_b, conv_w, conv_b, P, S);
    hipLaunchKernelGGL(k_scan2,   dim3(12, 8),    dim3(256), 0, stream, P, S);
    hipLaunchKernelGGL(k_scan3,   dim3(NCHUNK, 8), dim3(192), 0, stream,
                       u_raw, dtarr, Barr, Carr, A_log, dt_w, dt_b, conv_w, conv_b,
                       S, Dp, res, yfin);
    hipLaunchKernelGGL(k_outproj, dim3(32, 2, 8), dim3(256), 0, stream, yfin, out_w, (float*)d_out);
}